// Round 17
// baseline (162.182 us; speedup 1.0000x reference)
//
#include <hip/hip_runtime.h>

typedef unsigned short u16;
typedef unsigned int u32;
typedef short bf16x8 __attribute__((ext_vector_type(8)));
typedef float f32x4 __attribute__((ext_vector_type(4)));

// float -> bf16 bits, round-to-nearest-even (inputs never NaN here)
__device__ __forceinline__ u16 f2bf(float f) {
  union { float f; unsigned int u; } a; a.f = f;
  unsigned int r = a.u + 0x7FFFu + ((a.u >> 16) & 1u);
  return (u16)(r >> 16);
}

// ---- K1/K5: Y[o][p] = sum_c W[o*192+c] * X[c*4096+p]; OT out-rows x 2 pixels ----
template <int OT>
__global__ __launch_bounds__(256) void gemm192x2(const float* __restrict__ W,
                                                 const float* __restrict__ X,
                                                 float* __restrict__ Y) {
  __shared__ float wlds[OT * 192];
  int tid = threadIdx.x;
  int p = blockIdx.x * 512 + tid;      // pixel 0; pixel 1 = p + 256
  int o0 = blockIdx.y * OT;
  for (int i = tid; i < OT * 192; i += 256) wlds[i] = W[o0 * 192 + i];
  __syncthreads();
  float acc0[OT], acc1[OT];
  #pragma unroll
  for (int i = 0; i < OT; ++i) { acc0[i] = 0.f; acc1[i] = 0.f; }
  float xa0 = X[0 * 4096 + p],       xa1 = X[1 * 4096 + p];
  float xa2 = X[2 * 4096 + p],       xa3 = X[3 * 4096 + p];
  float xb0 = X[0 * 4096 + p + 256], xb1 = X[1 * 4096 + p + 256];
  float xb2 = X[2 * 4096 + p + 256], xb3 = X[3 * 4096 + p + 256];
  for (int c = 0; c < 192; c += 4) {
    float na0, na1, na2, na3, nb0, nb1, nb2, nb3;
    if (c < 188) {
      na0 = X[(c + 4) * 4096 + p];       na1 = X[(c + 5) * 4096 + p];
      na2 = X[(c + 6) * 4096 + p];       na3 = X[(c + 7) * 4096 + p];
      nb0 = X[(c + 4) * 4096 + p + 256]; nb1 = X[(c + 5) * 4096 + p + 256];
      nb2 = X[(c + 6) * 4096 + p + 256]; nb3 = X[(c + 7) * 4096 + p + 256];
    }
    #pragma unroll
    for (int oo = 0; oo < OT; ++oo) {
      float4 w4 = *(const float4*)&wlds[oo * 192 + c];  // broadcast b128
      acc0[oo] = fmaf(w4.x, xa0, fmaf(w4.y, xa1, fmaf(w4.z, xa2, fmaf(w4.w, xa3, acc0[oo]))));
      acc1[oo] = fmaf(w4.x, xb0, fmaf(w4.y, xb1, fmaf(w4.z, xb2, fmaf(w4.w, xb3, acc1[oo]))));
    }
    xa0 = na0; xa1 = na1; xa2 = na2; xa3 = na3;
    xb0 = nb0; xb1 = nb1; xb2 = nb2; xb3 = nb3;
  }
  #pragma unroll
  for (int oo = 0; oo < OT; ++oo) {
    Y[(size_t)(o0 + oo) * 4096 + p] = acc0[oo];
    Y[(size_t)(o0 + oo) * 4096 + p + 256] = acc1[oo];
  }
}

// ---- depthwise 3x3 (pad=1) for one channel/pixel, identical fmaf order to the
// original dwconv3 kernel (bit-identical results) ----
__device__ __forceinline__ float dw3(const float* __restrict__ ic,
                                     const float* __restrict__ wc,
                                     int y, int x) {
  float s = 0.f;
  #pragma unroll
  for (int i = 0; i < 3; ++i) {
    int yy = y + i - 1;
    if ((unsigned)yy >= 64u) continue;
    #pragma unroll
    for (int j = 0; j < 3; ++j) {
      int xx = x + j - 1;
      if ((unsigned)xx >= 64u) continue;
      s = fmaf(wc[i * 3 + j], ic[yy * 64 + xx], s);
    }
  }
  return s;
}

// ---- K2+K3 fused (FLAT-parallel, unlike R15's spilling version): block = one
// head x 32-aligned 32-pixel tile; grid 1024 = 4 blocks/CU, 16 waves/CU.
// Phase A: 256 threads x 9 independent ch-pixels of dwconv (no per-thread
// arrays -> no spill), staged in padded LDS. Phase B: Q/K L2-norm + bf16 pack
// (identical fmaf order -> bit-identical) and V pack with the A-frag key
// permutation, which maps each 32-slot half of a 64-key group onto itself:
// kp_local = ((px>>2)&3)*8 + ((px>>4)&1)*4 + (px&3)  (independent of half).
// Row d==24 = ones -> PV MFMA yields softmax denominator.
__global__ __launch_bounds__(256) void dwnv(const float* __restrict__ qkv,
                                            const float* __restrict__ wdw,
                                            u32* __restrict__ Qh32,
                                            u32* __restrict__ Kh32,
                                            u32* __restrict__ Vt32) {
  __shared__ float Sd[72 * 33];   // 9504 B: dwconv outputs [ch][px], pad 33
  __shared__ u32 Ql[32 * 17];     // 2176 B
  __shared__ u32 Kl[32 * 17];     // 2176 B
  __shared__ u16 Vl[32 * 32];     // 2048 B
  int t = threadIdx.x;
  int bid = blockIdx.x;           // 1024 = 8 heads x 128 tiles
  int h = bid >> 7;
  int p0 = (bid & 127) << 5;      // 32-aligned 32-pixel tile
  int y = p0 >> 6;
  int x0 = p0 & 63;               // 0 or 32
  u32* Vl32 = (u32*)Vl;
  // phase A: depthwise conv, 9 ch-px per thread (72 ch x 32 px = 2304)
  #pragma unroll
  for (int k = 0; k < 9; ++k) {
    int i = t + 256 * k;
    int ch = i >> 5, px = i & 31;
    int c = (ch < 24) ? (h * 24 + ch)
          : (ch < 48) ? (192 + h * 24 + (ch - 24))
                      : (384 + h * 24 + (ch - 48));
    Sd[ch * 33 + px] = dw3(qkv + (size_t)c * 4096, wdw + c * 9, y, x0 + px);
  }
  if (t < 112) Vl32[25 * 16 + t] = 0;   // zero V rows d=25..31 (no phase-A hazard)
  __syncthreads();
  const float QSC = 0.20412414523193154f * 1.4426950408889634f;  // 24^-0.5 * log2(e)
  if (t < 32) {                   // Q-norm, px = t
    int px = t;
    float s = 0.f;
    #pragma unroll
    for (int d = 0; d < 24; ++d) {
      float v = Sd[d * 33 + px];
      s = fmaf(v, v, s);
    }
    float iq = QSC / fmaxf(sqrtf(s), 1e-12f);  // F.normalize semantics
    #pragma unroll
    for (int j = 0; j < 12; ++j)
      Ql[px * 17 + j] = ((u32)f2bf(Sd[(2 * j + 1) * 33 + px] * iq) << 16) |
                        f2bf(Sd[(2 * j) * 33 + px] * iq);
    #pragma unroll
    for (int j = 12; j < 16; ++j) Ql[px * 17 + j] = 0;
  } else if (t < 64) {            // K-norm, px = t-32, ch base 24
    int px = t - 32;
    float s = 0.f;
    #pragma unroll
    for (int d = 0; d < 24; ++d) {
      float v = Sd[(24 + d) * 33 + px];
      s = fmaf(v, v, s);
    }
    float ik = 1.0f / fmaxf(sqrtf(s), 1e-12f);
    #pragma unroll
    for (int j = 0; j < 12; ++j)
      Kl[px * 17 + j] = ((u32)f2bf(Sd[(24 + 2 * j + 1) * 33 + px] * ik) << 16) |
                        f2bf(Sd[(24 + 2 * j) * 33 + px] * ik);
    #pragma unroll
    for (int j = 12; j < 16; ++j) Kl[px * 17 + j] = 0;
  } else if (t < 96) {            // V-pack, px = t-64, ch base 48
    int px = t - 64;
    int kp = (((px >> 2) & 3) << 3) | (((px >> 4) & 1) << 2) | (px & 3);
    #pragma unroll
    for (int dd = 0; dd < 24; ++dd)
      Vl[dd * 32 + kp] = f2bf(Sd[(48 + dd) * 33 + px]);
    Vl[24 * 32 + kp] = 0x3F80;    // bf16 1.0 (denominator row)
  }
  __syncthreads();
  // phase C: coalesced global writes
  size_t base = ((size_t)(h << 12) + p0) * 16;  // u32 index, Q/K rows [p][16]
  for (int i = t; i < 512; i += 256) {
    u32 li = (i >> 4) * 17 + (i & 15);
    Qh32[base + i] = Ql[li];
    Kh32[base + i] = Kl[li];
  }
  for (int i = t; i < 512; i += 256) {          // 32 d-rows x 16 u32
    int d = i >> 4, c2 = i & 15;
    Vt32[(((size_t)(h * 32 + d)) << 11) + (p0 >> 1) + c2] = Vl32[d * 16 + c2];
  }
}

// exp2 each element of two f32x4 (S^T regs r=0..3 = keys quad*4+r), truncate to
// bf16, pack into a PV A-fragment (slots j=0..3 from a, j=4..7 from b).
__device__ __forceinline__ bf16x8 pexp(f32x4 a, f32x4 b) {
  union { u32 u[4]; bf16x8 v; } x;
  u32 a0 = __float_as_uint(__builtin_amdgcn_exp2f(a[0]));
  u32 a1 = __float_as_uint(__builtin_amdgcn_exp2f(a[1]));
  u32 a2 = __float_as_uint(__builtin_amdgcn_exp2f(a[2]));
  u32 a3 = __float_as_uint(__builtin_amdgcn_exp2f(a[3]));
  u32 b0 = __float_as_uint(__builtin_amdgcn_exp2f(b[0]));
  u32 b1 = __float_as_uint(__builtin_amdgcn_exp2f(b[1]));
  u32 b2 = __float_as_uint(__builtin_amdgcn_exp2f(b[2]));
  u32 b3 = __float_as_uint(__builtin_amdgcn_exp2f(b[3]));
  x.u[0] = __builtin_amdgcn_perm(a1, a0, 0x07060302u);
  x.u[1] = __builtin_amdgcn_perm(a3, a2, 0x07060302u);
  x.u[2] = __builtin_amdgcn_perm(b1, b0, 0x07060302u);
  x.u[3] = __builtin_amdgcn_perm(b3, b2, 0x07060302u);
  return x.v;
}

// ---- K4: flash attention, register-resident P, 4 Q-frags/wave (64 q), zero
// global intermediates, K double-buffered (R16 — neutral but harmless; K/V
// latency is NOT the limiter per R14 vs R16 A/B). FROZEN this round: no
// counters available (below top-5 cutoff), no blind edits.
__global__ __launch_bounds__(512, 4) void attn(const u16* __restrict__ Qh,
                                               const u16* __restrict__ Kh,
                                               const u16* __restrict__ Vt,
                                               float* __restrict__ Y) {
  __shared__ float Sf[8 * 64 * 28];  // 57344 B epilogue staging
  int tid = threadIdx.x;
  int wave = tid >> 6, lane = tid & 63;
  int lo = lane & 15, hi = lane >> 4;
  int b = blockIdx.x;
  int head = b & 7;              // head == XCD (round-robin) -> K/V L2-resident
  int q0 = (b >> 3) << 6;        // 64 queries per block

  const u16* Kb = Kh + ((size_t)head << 17);
  const u16* Vb = Vt + ((size_t)head << 17);

  size_t qrow = (size_t)(head << 12) + q0 + lo;
  bf16x8 qf[4];
  #pragma unroll
  for (int f = 0; f < 4; ++f)
    qf[f] = *(const bf16x8*)(Qh + ((qrow + f * 16) << 5) + hi * 8);

  f32x4 zz = {0.f, 0.f, 0.f, 0.f};
  f32x4 oA[4], oB[4];
  #pragma unroll
  for (int f = 0; f < 4; ++f) { oA[f] = zz; oB[f] = zz; }

  int kbase = wave << 9;                        // 512 keys per wave

  bf16x8 kf[2][4];
  #pragma unroll
  for (int j = 0; j < 4; ++j)
    kf[0][j] = *(const bf16x8*)(Kb + (((size_t)(kbase + j * 16 + lo)) << 5) + hi * 8);

  #pragma unroll
  for (int it = 0; it < 8; ++it) {              // 8 tiles of 64 keys
    int cur = it & 1;
    int k0 = kbase + it * 64;
    bf16x8 vf[4];
    vf[0] = *(const bf16x8*)(Vb + (((size_t)(lo)) << 12) + k0 + hi * 8);
    vf[1] = *(const bf16x8*)(Vb + (((size_t)(16 + lo)) << 12) + k0 + hi * 8);
    vf[2] = *(const bf16x8*)(Vb + (((size_t)(lo)) << 12) + k0 + 32 + hi * 8);
    vf[3] = *(const bf16x8*)(Vb + (((size_t)(16 + lo)) << 12) + k0 + 32 + hi * 8);
    if (it < 7) {                               // prefetch next tile's K
      #pragma unroll
      for (int j = 0; j < 4; ++j)
        kf[cur ^ 1][j] = *(const bf16x8*)(Kb + (((size_t)(k0 + 64 + j * 16 + lo)) << 5) + hi * 8);
    }
    #pragma unroll
    for (int f = 0; f < 4; ++f) {
      f32x4 t0 = __builtin_amdgcn_mfma_f32_16x16x32_bf16(kf[cur][0], qf[f], zz, 0, 0, 0);
      f32x4 t1 = __builtin_amdgcn_mfma_f32_16x16x32_bf16(kf[cur][1], qf[f], zz, 0, 0, 0);
      f32x4 t2 = __builtin_amdgcn_mfma_f32_16x16x32_bf16(kf[cur][2], qf[f], zz, 0, 0, 0);
      f32x4 t3 = __builtin_amdgcn_mfma_f32_16x16x32_bf16(kf[cur][3], qf[f], zz, 0, 0, 0);
      bf16x8 a0 = pexp(t0, t1);
      bf16x8 a1 = pexp(t2, t3);
      oA[f] = __builtin_amdgcn_mfma_f32_16x16x32_bf16(a0, vf[0], oA[f], 0, 0, 0);
      oB[f] = __builtin_amdgcn_mfma_f32_16x16x32_bf16(a0, vf[1], oB[f], 0, 0, 0);
      oA[f] = __builtin_amdgcn_mfma_f32_16x16x32_bf16(a1, vf[2], oA[f], 0, 0, 0);
      oB[f] = __builtin_amdgcn_mfma_f32_16x16x32_bf16(a1, vf[3], oB[f], 0, 0, 0);
    }
  }

  // phase 1: stage fp32 C-layout (num cols 0..23, den col 24) into OWN strip.
  int sb = wave * (64 * 28);
  #pragma unroll
  for (int f = 0; f < 4; ++f) {
    #pragma unroll
    for (int r = 0; r < 4; ++r) {
      int row = f * 16 + hi * 4 + r;
      Sf[sb + row * 28 + lo] = oA[f][r];
      if (lo < 8) Sf[sb + row * 28 + 16 + lo] = oB[f][r];
      if (lo == 8) Sf[sb + row * 28 + 24] = oB[f][r];   // ones-row = denominator
    }
  }
  __syncthreads();
  // phase 2: reduce the 8 K-eighths, normalize, direct coalesced store.
  int q = tid & 63;              // local query row
  int d0 = tid >> 6;             // 0..7
  int base0 = q * 28;
  const int SS = 64 * 28;
  float den = 0.f;
  #pragma unroll
  for (int s = 0; s < 8; ++s) den += Sf[base0 + s * SS + 24];
  float inv = 1.0f / den;
  float* Yh = Y + ((size_t)head * 24) * 4096 + q0 + q;
  #pragma unroll
  for (int dp = 0; dp < 3; ++dp) {
    int dd = dp * 8 + d0;
    float v = 0.f;
    #pragma unroll
    for (int s = 0; s < 8; ++s) v += Sf[base0 + s * SS + dd];
    Yh[(size_t)dd * 4096] = v * inv;
  }
}

extern "C" void kernel_launch(void* const* d_in, const int* in_sizes, int n_in,
                              void* d_out, int out_size, void* d_ws, size_t ws_size,
                              hipStream_t stream) {
  const float* x      = (const float*)d_in[0];  // [192][4096]
  const float* w_qkv  = (const float*)d_in[1];  // [576][192]
  const float* w_dw   = (const float*)d_in[2];  // [576][9]
  const float* w_proj = (const float*)d_in[3];  // [192][192]
  float* out = (float*)d_out;                   // [192][4096] fp32

  char* ws = (char*)d_ws;
  float* qkv    = (float*)(ws);                 // 9437184 (dead after dwnv)
  u16*   Qh     = (u16*)  (ws + 18874368);      // 2097152
  u16*   Kh     = (u16*)  (ws + 20971520);      // 2097152
  u16*   Vt     = (u16*)  (ws + 23068672);      // 2097152  (end 25165824)
  float* attn_o = (float*)(ws + 13107200);      // 3145728 (disjoint from qkv)

  // qkv GEMM: PX=2, OT=6, grid (8,96)=768 blocks = 3 blocks/CU
  gemm192x2<6><<<dim3(8, 96), 256, 0, stream>>>(w_qkv, x, qkv);
  // fused depthwise+normalize+pack: 1024 blocks (head x 32-px tile), flat-parallel
  dwnv<<<dim3(1024), 256, 0, stream>>>(qkv, w_dw, (u32*)Qh, (u32*)Kh, (u32*)Vt);
  // 512 blocks x 512 threads; 4 q-frags/wave, register-resident P, K dbuf
  attn<<<dim3(512), 512, 0, stream>>>(Qh, Kh, Vt, attn_o);
  // proj GEMM: PX=2, OT=3, grid (8,64)=512 blocks = 2 blocks/CU
  gemm192x2<3><<<dim3(8, 64), 256, 0, stream>>>(w_proj, attn_o, out);
}

// Round 18
// 145.122 us; speedup vs baseline: 1.1176x; 1.1176x over previous
//
#include <hip/hip_runtime.h>

typedef unsigned short u16;
typedef unsigned int u32;
typedef short bf16x8 __attribute__((ext_vector_type(8)));
typedef float f32x4 __attribute__((ext_vector_type(4)));

// float -> bf16 bits, round-to-nearest-even (inputs never NaN here)
__device__ __forceinline__ u16 f2bf(float f) {
  union { float f; unsigned int u; } a; a.f = f;
  unsigned int r = a.u + 0x7FFFu + ((a.u >> 16) & 1u);
  return (u16)(r >> 16);
}

// ---- K5 (proj): Y[o][p] = sum_c W[o*192+c] * X[c*4096+p]; OT out-rows x 2 px ----
template <int OT>
__global__ __launch_bounds__(256) void gemm192x2(const float* __restrict__ W,
                                                 const float* __restrict__ X,
                                                 float* __restrict__ Y) {
  __shared__ float wlds[OT * 192];
  int tid = threadIdx.x;
  int p = blockIdx.x * 512 + tid;      // pixel 0; pixel 1 = p + 256
  int o0 = blockIdx.y * OT;
  for (int i = tid; i < OT * 192; i += 256) wlds[i] = W[o0 * 192 + i];
  __syncthreads();
  float acc0[OT], acc1[OT];
  #pragma unroll
  for (int i = 0; i < OT; ++i) { acc0[i] = 0.f; acc1[i] = 0.f; }
  float xa0 = X[0 * 4096 + p],       xa1 = X[1 * 4096 + p];
  float xa2 = X[2 * 4096 + p],       xa3 = X[3 * 4096 + p];
  float xb0 = X[0 * 4096 + p + 256], xb1 = X[1 * 4096 + p + 256];
  float xb2 = X[2 * 4096 + p + 256], xb3 = X[3 * 4096 + p + 256];
  for (int c = 0; c < 192; c += 4) {
    float na0, na1, na2, na3, nb0, nb1, nb2, nb3;
    if (c < 188) {
      na0 = X[(c + 4) * 4096 + p];       na1 = X[(c + 5) * 4096 + p];
      na2 = X[(c + 6) * 4096 + p];       na3 = X[(c + 7) * 4096 + p];
      nb0 = X[(c + 4) * 4096 + p + 256]; nb1 = X[(c + 5) * 4096 + p + 256];
      nb2 = X[(c + 6) * 4096 + p + 256]; nb3 = X[(c + 7) * 4096 + p + 256];
    }
    #pragma unroll
    for (int oo = 0; oo < OT; ++oo) {
      float4 w4 = *(const float4*)&wlds[oo * 192 + c];  // broadcast b128
      acc0[oo] = fmaf(w4.x, xa0, fmaf(w4.y, xa1, fmaf(w4.z, xa2, fmaf(w4.w, xa3, acc0[oo]))));
      acc1[oo] = fmaf(w4.x, xb0, fmaf(w4.y, xb1, fmaf(w4.z, xb2, fmaf(w4.w, xb3, acc1[oo]))));
    }
    xa0 = na0; xa1 = na1; xa2 = na2; xa3 = na3;
    xb0 = nb0; xb1 = nb1; xb2 = nb2; xb3 = nb3;
  }
  #pragma unroll
  for (int oo = 0; oo < OT; ++oo) {
    Y[(size_t)(o0 + oo) * 4096 + p] = acc0[oo];
    Y[(size_t)(o0 + oo) * 4096 + p + 256] = acc1[oo];
  }
}

// ---- K0: prep for MFMA qkv GEMM. Blocks 0..127: transpose X [192][4096] fp32
// -> Xt [4096][192] bf16 (32-px tiles via LDS). Blocks 128..181: convert W ->
// bf16. RNE rounding; error budget: bf16 qkv adds ~0.3% rel to q/k/v, mostly
// cancelled by L2-norm for q/k; predicted absmax ~2-3e-5 vs 7.9e-5 threshold.
__global__ __launch_bounds__(256) void prep(const float* __restrict__ X,
                                            const float* __restrict__ W,
                                            u16* __restrict__ Xt,
                                            u16* __restrict__ Wb) {
  int b = blockIdx.x;
  int t = threadIdx.x;
  if (b < 128) {
    __shared__ float Xl[192 * 33];   // 25344 B, +1 pad
    int p0 = b << 5;
    int px = t & 31, cs = t >> 5;    // 8 c-groups
    #pragma unroll
    for (int i = 0; i < 24; ++i) {
      int c = cs * 24 + i;
      Xl[c * 33 + px] = X[(size_t)c * 4096 + p0 + px];
    }
    __syncthreads();
    int pxo = t >> 3, j0 = (t & 7) * 12;     // 32 px x 96 u32 rows
    u32* Xt32 = (u32*)Xt;
    #pragma unroll
    for (int jj = 0; jj < 12; ++jj) {
      int j = j0 + jj;
      u32 v = ((u32)f2bf(Xl[(2 * j + 1) * 33 + pxo]) << 16) |
              f2bf(Xl[(2 * j) * 33 + pxo]);
      Xt32[(size_t)(p0 + pxo) * 96 + j] = v;
    }
  } else {
    int idx = (b - 128) * 2048 + t * 8;      // 54 blocks x 2048 = 110592
    #pragma unroll
    for (int i = 0; i < 8; ++i) Wb[idx + i] = f2bf(W[idx + i]);
  }
}

// ---- K1: qkv GEMM on MFMA. Y[576][4096] fp32 = Wb[576][192] x Xt[4096][192]
// (both bf16, K=192 = 6 MFMA k-steps). Wave tile 32m x 32n (2x2 frags); block
// 4 waves = 32m x 128n; grid (32,18) = 576 blocks. Fragment layouts: A/B =
// [idx=lane&15][k=quad*8+j] (same rule as the attn QK path, HW-verified);
// D[row=m][col=n], col=lane&15, row=quad*4+r.
__global__ __launch_bounds__(256) void mqkv(const u16* __restrict__ Wb,
                                            const u16* __restrict__ Xt,
                                            float* __restrict__ Y) {
  int tid = threadIdx.x;
  int wave = tid >> 6, lane = tid & 63;
  int lo = lane & 15, hi = lane >> 4;
  int m0 = blockIdx.y << 5;
  int n0 = (blockIdx.x << 7) + (wave << 5);
  f32x4 zz = {0.f, 0.f, 0.f, 0.f};
  f32x4 acc00 = zz, acc01 = zz, acc10 = zz, acc11 = zz;
  #pragma unroll
  for (int k0 = 0; k0 < 192; k0 += 32) {
    bf16x8 a0 = *(const bf16x8*)(Wb + (size_t)(m0 + lo) * 192 + k0 + hi * 8);
    bf16x8 a1 = *(const bf16x8*)(Wb + (size_t)(m0 + 16 + lo) * 192 + k0 + hi * 8);
    bf16x8 b0 = *(const bf16x8*)(Xt + (size_t)(n0 + lo) * 192 + k0 + hi * 8);
    bf16x8 b1 = *(const bf16x8*)(Xt + (size_t)(n0 + 16 + lo) * 192 + k0 + hi * 8);
    acc00 = __builtin_amdgcn_mfma_f32_16x16x32_bf16(a0, b0, acc00, 0, 0, 0);
    acc01 = __builtin_amdgcn_mfma_f32_16x16x32_bf16(a0, b1, acc01, 0, 0, 0);
    acc10 = __builtin_amdgcn_mfma_f32_16x16x32_bf16(a1, b0, acc10, 0, 0, 0);
    acc11 = __builtin_amdgcn_mfma_f32_16x16x32_bf16(a1, b1, acc11, 0, 0, 0);
  }
  #pragma unroll
  for (int r = 0; r < 4; ++r) {
    Y[(size_t)(m0 + hi * 4 + r) * 4096 + n0 + lo] = acc00[r];
    Y[(size_t)(m0 + hi * 4 + r) * 4096 + n0 + 16 + lo] = acc01[r];
    Y[(size_t)(m0 + 16 + hi * 4 + r) * 4096 + n0 + lo] = acc10[r];
    Y[(size_t)(m0 + 16 + hi * 4 + r) * 4096 + n0 + 16 + lo] = acc11[r];
  }
}

// ---- K2: depthwise 3x3, pad=1, on [576][64][64] (1 ch/thread, 9216 blocks —
// both fusion attempts R15/R17 regressed; this flat form is the floor) ----
__global__ __launch_bounds__(256) void dwconv3(const float* __restrict__ in,
                                               const float* __restrict__ w,
                                               float* __restrict__ out) {
  int idx = blockIdx.x * 256 + threadIdx.x;  // c*4096 + p
  int c = idx >> 12;
  int p = idx & 4095;
  int y = p >> 6, x = p & 63;
  const float* wc = w + c * 9;
  const float* ic = in + (size_t)c * 4096;
  float s = 0.f;
  #pragma unroll
  for (int i = 0; i < 3; ++i) {
    int yy = y + i - 1;
    if ((unsigned)yy >= 64u) continue;
    #pragma unroll
    for (int j = 0; j < 3; ++j) {
      int xx = x + j - 1;
      if ((unsigned)xx >= 64u) continue;
      s = fmaf(wc[i * 3 + j], ic[yy * 64 + xx], s);
    }
  }
  out[idx] = s;
}

// ---- K3: fused normalize+pack. 256 blocks; per block: 128 pixels of one head.
// Threads 0..127: Q+K normalize+pack ([h][p][32] bf16). Threads 128..255: V pack.
// V key-permutation matches the REGISTER A-frag layout of the transposed-S trick:
// within each 64-key group, key k (b=bit4 of k&31, quad=(k>>2)&3, r=k&3) lands at
// position (k&32) | quad*8 + b*4 + r. Row d==24 = ones -> PV yields denominator.
__global__ __launch_bounds__(256) void nvpack(const float* __restrict__ qkv,
                                              u32* __restrict__ Qh32,
                                              u32* __restrict__ Kh32,
                                              u32* __restrict__ Vt32) {
  __shared__ u32 Ql[128 * 17];
  __shared__ u32 Kl[128 * 17];
  __shared__ u16 Vl[32 * 128];
  int t = threadIdx.x;
  int bid = blockIdx.x;          // 256 blocks
  int h = bid >> 5;
  int p0 = (bid & 31) << 7;      // 128-pixel tile
  u32* Vl32 = (u32*)Vl;
  const float QSC = 0.20412414523193154f * 1.4426950408889634f;  // 24^-0.5 * log2(e)
  if (t < 128) {
    int p = p0 + t;
    float qv[24], kv[24];
    float sq = 0.f, sk = 0.f;
    #pragma unroll
    for (int d = 0; d < 24; ++d) {
      qv[d] = qkv[(size_t)(h * 24 + d) * 4096 + p];
      sq = fmaf(qv[d], qv[d], sq);
    }
    #pragma unroll
    for (int d = 0; d < 24; ++d) {
      kv[d] = qkv[(size_t)(192 + h * 24 + d) * 4096 + p];
      sk = fmaf(kv[d], kv[d], sk);
    }
    float iq = QSC / fmaxf(sqrtf(sq), 1e-12f);  // F.normalize: x / max(||x||, eps)
    float ik = 1.0f / fmaxf(sqrtf(sk), 1e-12f);
    u32* qrow = Ql + t * 17;
    u32* krow = Kl + t * 17;
    #pragma unroll
    for (int j = 0; j < 12; ++j) {
      qrow[j] = ((u32)f2bf(qv[2 * j + 1] * iq) << 16) | f2bf(qv[2 * j] * iq);
      krow[j] = ((u32)f2bf(kv[2 * j + 1] * ik) << 16) | f2bf(kv[2 * j] * ik);
    }
    #pragma unroll
    for (int j = 12; j < 16; ++j) { qrow[j] = 0; krow[j] = 0; }
  } else {
    int tl = t - 128;
    int p = p0 + tl;
    // A-frag key permutation (see header comment)
    int kp = (tl & ~63) | (tl & 32) | (((tl >> 2) & 3) << 3) |
             (((tl >> 4) & 1) << 2) | (tl & 3);
    #pragma unroll
    for (int d = 0; d < 24; ++d)
      Vl[d * 128 + kp] = f2bf(qkv[(size_t)(384 + h * 24 + d) * 4096 + p]);
    Vl[24 * 128 + kp] = 0x3F80;  // bf16 1.0
  }
  for (int i = t; i < 7 * 64; i += 256) Vl32[25 * 64 + i] = 0;  // zero d=25..31
  __syncthreads();
  size_t base = ((size_t)(h << 12) + p0) * 16;
  for (int i = t; i < 2048; i += 256) {
    u32 li = (i >> 4) * 17 + (i & 15);
    Qh32[base + i] = Ql[li];
    Kh32[base + i] = Kl[li];
  }
  for (int i = t; i < 2048; i += 256) {
    int d = i >> 6, c = i & 63;
    Vt32[(((size_t)(h * 32 + d)) << 11) + (p0 >> 1) + c] = Vl32[d * 64 + c];
  }
}

// exp2 each element of two f32x4 (S^T regs r=0..3 = keys quad*4+r), truncate to
// bf16, pack into a PV A-fragment (slots j=0..3 from a, j=4..7 from b).
__device__ __forceinline__ bf16x8 pexp(f32x4 a, f32x4 b) {
  union { u32 u[4]; bf16x8 v; } x;
  u32 a0 = __float_as_uint(__builtin_amdgcn_exp2f(a[0]));
  u32 a1 = __float_as_uint(__builtin_amdgcn_exp2f(a[1]));
  u32 a2 = __float_as_uint(__builtin_amdgcn_exp2f(a[2]));
  u32 a3 = __float_as_uint(__builtin_amdgcn_exp2f(a[3]));
  u32 b0 = __float_as_uint(__builtin_amdgcn_exp2f(b[0]));
  u32 b1 = __float_as_uint(__builtin_amdgcn_exp2f(b[1]));
  u32 b2 = __float_as_uint(__builtin_amdgcn_exp2f(b[2]));
  u32 b3 = __float_as_uint(__builtin_amdgcn_exp2f(b[3]));
  x.u[0] = __builtin_amdgcn_perm(a1, a0, 0x07060302u);
  x.u[1] = __builtin_amdgcn_perm(a3, a2, 0x07060302u);
  x.u[2] = __builtin_amdgcn_perm(b1, b0, 0x07060302u);
  x.u[3] = __builtin_amdgcn_perm(b3, b2, 0x07060302u);
  return x.v;
}

// ---- K4: flash attention, register-resident P, 4 Q-frags/wave (64 q), zero
// global intermediates, K double-buffered. FROZEN (R14/R16 best, ~31us).
__global__ __launch_bounds__(512, 4) void attn(const u16* __restrict__ Qh,
                                               const u16* __restrict__ Kh,
                                               const u16* __restrict__ Vt,
                                               float* __restrict__ Y) {
  __shared__ float Sf[8 * 64 * 28];  // 57344 B epilogue staging
  int tid = threadIdx.x;
  int wave = tid >> 6, lane = tid & 63;
  int lo = lane & 15, hi = lane >> 4;
  int b = blockIdx.x;
  int head = b & 7;              // head == XCD (round-robin) -> K/V L2-resident
  int q0 = (b >> 3) << 6;        // 64 queries per block

  const u16* Kb = Kh + ((size_t)head << 17);
  const u16* Vb = Vt + ((size_t)head << 17);

  size_t qrow = (size_t)(head << 12) + q0 + lo;
  bf16x8 qf[4];
  #pragma unroll
  for (int f = 0; f < 4; ++f)
    qf[f] = *(const bf16x8*)(Qh + ((qrow + f * 16) << 5) + hi * 8);

  f32x4 zz = {0.f, 0.f, 0.f, 0.f};
  f32x4 oA[4], oB[4];
  #pragma unroll
  for (int f = 0; f < 4; ++f) { oA[f] = zz; oB[f] = zz; }

  int kbase = wave << 9;                        // 512 keys per wave

  bf16x8 kf[2][4];
  #pragma unroll
  for (int j = 0; j < 4; ++j)
    kf[0][j] = *(const bf16x8*)(Kb + (((size_t)(kbase + j * 16 + lo)) << 5) + hi * 8);

  #pragma unroll
  for (int it = 0; it < 8; ++it) {              // 8 tiles of 64 keys
    int cur = it & 1;
    int k0 = kbase + it * 64;
    bf16x8 vf[4];
    vf[0] = *(const bf16x8*)(Vb + (((size_t)(lo)) << 12) + k0 + hi * 8);
    vf[1] = *(const bf16x8*)(Vb + (((size_t)(16 + lo)) << 12) + k0 + hi * 8);
    vf[2] = *(const bf16x8*)(Vb + (((size_t)(lo)) << 12) + k0 + 32 + hi * 8);
    vf[3] = *(const bf16x8*)(Vb + (((size_t)(16 + lo)) << 12) + k0 + 32 + hi * 8);
    if (it < 7) {                               // prefetch next tile's K
      #pragma unroll
      for (int j = 0; j < 4; ++j)
        kf[cur ^ 1][j] = *(const bf16x8*)(Kb + (((size_t)(k0 + 64 + j * 16 + lo)) << 5) + hi * 8);
    }
    #pragma unroll
    for (int f = 0; f < 4; ++f) {
      f32x4 t0 = __builtin_amdgcn_mfma_f32_16x16x32_bf16(kf[cur][0], qf[f], zz, 0, 0, 0);
      f32x4 t1 = __builtin_amdgcn_mfma_f32_16x16x32_bf16(kf[cur][1], qf[f], zz, 0, 0, 0);
      f32x4 t2 = __builtin_amdgcn_mfma_f32_16x16x32_bf16(kf[cur][2], qf[f], zz, 0, 0, 0);
      f32x4 t3 = __builtin_amdgcn_mfma_f32_16x16x32_bf16(kf[cur][3], qf[f], zz, 0, 0, 0);
      bf16x8 a0 = pexp(t0, t1);
      bf16x8 a1 = pexp(t2, t3);
      oA[f] = __builtin_amdgcn_mfma_f32_16x16x32_bf16(a0, vf[0], oA[f], 0, 0, 0);
      oB[f] = __builtin_amdgcn_mfma_f32_16x16x32_bf16(a0, vf[1], oB[f], 0, 0, 0);
      oA[f] = __builtin_amdgcn_mfma_f32_16x16x32_bf16(a1, vf[2], oA[f], 0, 0, 0);
      oB[f] = __builtin_amdgcn_mfma_f32_16x16x32_bf16(a1, vf[3], oB[f], 0, 0, 0);
    }
  }

  // phase 1: stage fp32 C-layout (num cols 0..23, den col 24) into OWN strip.
  int sb = wave * (64 * 28);
  #pragma unroll
  for (int f = 0; f < 4; ++f) {
    #pragma unroll
    for (int r = 0; r < 4; ++r) {
      int row = f * 16 + hi * 4 + r;
      Sf[sb + row * 28 + lo] = oA[f][r];
      if (lo < 8) Sf[sb + row * 28 + 16 + lo] = oB[f][r];
      if (lo == 8) Sf[sb + row * 28 + 24] = oB[f][r];   // ones-row = denominator
    }
  }
  __syncthreads();
  // phase 2: reduce the 8 K-eighths, normalize, direct coalesced store.
  int q = tid & 63;              // local query row
  int d0 = tid >> 6;             // 0..7
  int base0 = q * 28;
  const int SS = 64 * 28;
  float den = 0.f;
  #pragma unroll
  for (int s = 0; s < 8; ++s) den += Sf[base0 + s * SS + 24];
  float inv = 1.0f / den;
  float* Yh = Y + ((size_t)head * 24) * 4096 + q0 + q;
  #pragma unroll
  for (int dp = 0; dp < 3; ++dp) {
    int dd = dp * 8 + d0;
    float v = 0.f;
    #pragma unroll
    for (int s = 0; s < 8; ++s) v += Sf[base0 + s * SS + dd];
    Yh[(size_t)dd * 4096] = v * inv;
  }
}

extern "C" void kernel_launch(void* const* d_in, const int* in_sizes, int n_in,
                              void* d_out, int out_size, void* d_ws, size_t ws_size,
                              hipStream_t stream) {
  const float* x      = (const float*)d_in[0];  // [192][4096]
  const float* w_qkv  = (const float*)d_in[1];  // [576][192]
  const float* w_dw   = (const float*)d_in[2];  // [576][9]
  const float* w_proj = (const float*)d_in[3];  // [192][192]
  float* out = (float*)d_out;                   // [192][4096] fp32

  char* ws = (char*)d_ws;
  float* qkv    = (float*)(ws);                 // 9437184  (dead after dwconv3)
  float* qkvd   = (float*)(ws + 9437184);       // 9437184  (dead after nvpack)
  u16*   Qh     = (u16*)  (ws + 18874368);      // 2097152
  u16*   Kh     = (u16*)  (ws + 20971520);      // 2097152
  u16*   Vt     = (u16*)  (ws + 23068672);      // 2097152  (end 25165824)
  u16*   Xt     = (u16*)  (ws + 25165824);      // 1572864  (bf16 X^T)
  u16*   Wb     = (u16*)  (ws + 26738688);      // 221184   (end 26959872)
  float* attn_o = (float*)(ws + 13107200);      // 3145728 (inside dead-qkvd)

  // prep: X transpose->bf16 (128 blocks) + W->bf16 (54 blocks)
  prep<<<dim3(182), 256, 0, stream>>>(x, w_qkv, Xt, Wb);
  // qkv GEMM on MFMA: grid (32 n-tiles, 18 m-tiles) = 576 blocks
  mqkv<<<dim3(32, 18), 256, 0, stream>>>(Wb, Xt, qkv);
  dwconv3<<<dim3(9216), 256, 0, stream>>>(qkv, w_dw, qkvd);
  nvpack<<<dim3(256), 256, 0, stream>>>(qkvd, (u32*)Qh, (u32*)Kh, (u32*)Vt);
  // 512 blocks x 512 threads; 4 q-frags/wave, register-resident P, K dbuf
  attn<<<dim3(512), 512, 0, stream>>>(Qh, Kh, Vt, attn_o);
  // proj GEMM (fp32): PX=2, OT=3, grid (8,64)=512 blocks
  gemm192x2<3><<<dim3(8, 64), 256, 0, stream>>>(w_proj, attn_o, out);
}

// Round 19
// 128.829 us; speedup vs baseline: 1.2589x; 1.1265x over previous
//
#include <hip/hip_runtime.h>

typedef unsigned short u16;
typedef unsigned int u32;
typedef short bf16x8 __attribute__((ext_vector_type(8)));
typedef float f32x4 __attribute__((ext_vector_type(4)));

// float -> bf16 bits, round-to-nearest-even (inputs never NaN here)
__device__ __forceinline__ u16 f2bf(float f) {
  union { float f; unsigned int u; } a; a.f = f;
  unsigned int r = a.u + 0x7FFFu + ((a.u >> 16) & 1u);
  return (u16)(r >> 16);
}

// ---- K0: prep. Blocks 0..127: transpose X [192][4096] fp32 -> Xt [4096][192]
// bf16 (32-px tiles via LDS). Blocks 128..181: w_qkv -> bf16. Blocks 182..199:
// w_proj -> bf16. RNE rounding (error model validated in R18: +~1e-5 absmax).
__global__ __launch_bounds__(256) void prep(const float* __restrict__ X,
                                            const float* __restrict__ W,
                                            const float* __restrict__ Wp,
                                            u16* __restrict__ Xt,
                                            u16* __restrict__ Wb,
                                            u16* __restrict__ Wpb) {
  int b = blockIdx.x;
  int t = threadIdx.x;
  if (b < 128) {
    __shared__ float Xl[192 * 33];   // 25344 B, +1 pad
    int p0 = b << 5;
    int px = t & 31, cs = t >> 5;    // 8 c-groups
    #pragma unroll
    for (int i = 0; i < 24; ++i) {
      int c = cs * 24 + i;
      Xl[c * 33 + px] = X[(size_t)c * 4096 + p0 + px];
    }
    __syncthreads();
    int pxo = t >> 3, j0 = (t & 7) * 12;     // 32 px x 96 u32 rows
    u32* Xt32 = (u32*)Xt;
    #pragma unroll
    for (int jj = 0; jj < 12; ++jj) {
      int j = j0 + jj;
      u32 v = ((u32)f2bf(Xl[(2 * j + 1) * 33 + pxo]) << 16) |
              f2bf(Xl[(2 * j) * 33 + pxo]);
      Xt32[(size_t)(p0 + pxo) * 96 + j] = v;
    }
  } else if (b < 182) {
    int idx = (b - 128) * 2048 + t * 8;      // 54 blocks x 2048 = 110592
    #pragma unroll
    for (int i = 0; i < 8; ++i) Wb[idx + i] = f2bf(W[idx + i]);
  } else {
    int idx = (b - 182) * 2048 + t * 8;      // 18 blocks x 2048 = 36864
    #pragma unroll
    for (int i = 0; i < 8; ++i) Wpb[idx + i] = f2bf(Wp[idx + i]);
  }
}

// ---- K1 (and K5): MFMA GEMM. Y[M][4096] fp32 = A[M][192] x B[4096][192]
// (both bf16, K=192 = 6 MFMA k-steps). Wave tile 32m x 32n (2x2 frags); block
// 4 waves = 32m x 128n; grid (32, M/32). Fragment layouts: A/B =
// [idx=lane&15][k=quad*8+j] (HW-verified, same rule as attn QK);
// D[row=m][col=n], col=lane&15, row=quad*4+r.
__global__ __launch_bounds__(256) void mqkv(const u16* __restrict__ Wb,
                                            const u16* __restrict__ Xt,
                                            float* __restrict__ Y) {
  int tid = threadIdx.x;
  int wave = tid >> 6, lane = tid & 63;
  int lo = lane & 15, hi = lane >> 4;
  int m0 = blockIdx.y << 5;
  int n0 = (blockIdx.x << 7) + (wave << 5);
  f32x4 zz = {0.f, 0.f, 0.f, 0.f};
  f32x4 acc00 = zz, acc01 = zz, acc10 = zz, acc11 = zz;
  #pragma unroll
  for (int k0 = 0; k0 < 192; k0 += 32) {
    bf16x8 a0 = *(const bf16x8*)(Wb + (size_t)(m0 + lo) * 192 + k0 + hi * 8);
    bf16x8 a1 = *(const bf16x8*)(Wb + (size_t)(m0 + 16 + lo) * 192 + k0 + hi * 8);
    bf16x8 b0 = *(const bf16x8*)(Xt + (size_t)(n0 + lo) * 192 + k0 + hi * 8);
    bf16x8 b1 = *(const bf16x8*)(Xt + (size_t)(n0 + 16 + lo) * 192 + k0 + hi * 8);
    acc00 = __builtin_amdgcn_mfma_f32_16x16x32_bf16(a0, b0, acc00, 0, 0, 0);
    acc01 = __builtin_amdgcn_mfma_f32_16x16x32_bf16(a0, b1, acc01, 0, 0, 0);
    acc10 = __builtin_amdgcn_mfma_f32_16x16x32_bf16(a1, b0, acc10, 0, 0, 0);
    acc11 = __builtin_amdgcn_mfma_f32_16x16x32_bf16(a1, b1, acc11, 0, 0, 0);
  }
  #pragma unroll
  for (int r = 0; r < 4; ++r) {
    Y[(size_t)(m0 + hi * 4 + r) * 4096 + n0 + lo] = acc00[r];
    Y[(size_t)(m0 + hi * 4 + r) * 4096 + n0 + 16 + lo] = acc01[r];
    Y[(size_t)(m0 + 16 + hi * 4 + r) * 4096 + n0 + lo] = acc10[r];
    Y[(size_t)(m0 + 16 + hi * 4 + r) * 4096 + n0 + 16 + lo] = acc11[r];
  }
}

// ---- K2: depthwise 3x3, pad=1, on [576][64][64] (1 ch/thread, 9216 blocks —
// both fusion attempts R15/R17 regressed; this flat form is the floor) ----
__global__ __launch_bounds__(256) void dwconv3(const float* __restrict__ in,
                                               const float* __restrict__ w,
                                               float* __restrict__ out) {
  int idx = blockIdx.x * 256 + threadIdx.x;  // c*4096 + p
  int c = idx >> 12;
  int p = idx & 4095;
  int y = p >> 6, x = p & 63;
  const float* wc = w + c * 9;
  const float* ic = in + (size_t)c * 4096;
  float s = 0.f;
  #pragma unroll
  for (int i = 0; i < 3; ++i) {
    int yy = y + i - 1;
    if ((unsigned)yy >= 64u) continue;
    #pragma unroll
    for (int j = 0; j < 3; ++j) {
      int xx = x + j - 1;
      if ((unsigned)xx >= 64u) continue;
      s = fmaf(wc[i * 3 + j], ic[yy * 64 + xx], s);
    }
  }
  out[idx] = s;
}

// ---- K3: fused normalize+pack. 256 blocks; per block: 128 pixels of one head.
// Threads 0..127: Q+K normalize+pack ([h][p][32] bf16). Threads 128..255: V pack.
// V key-permutation matches the REGISTER A-frag layout of the transposed-S trick:
// within each 64-key group, key k (b=bit4 of k&31, quad=(k>>2)&3, r=k&3) lands at
// position (k&32) | quad*8 + b*4 + r. Row d==24 = ones -> PV yields denominator.
__global__ __launch_bounds__(256) void nvpack(const float* __restrict__ qkv,
                                              u32* __restrict__ Qh32,
                                              u32* __restrict__ Kh32,
                                              u32* __restrict__ Vt32) {
  __shared__ u32 Ql[128 * 17];
  __shared__ u32 Kl[128 * 17];
  __shared__ u16 Vl[32 * 128];
  int t = threadIdx.x;
  int bid = blockIdx.x;          // 256 blocks
  int h = bid >> 5;
  int p0 = (bid & 31) << 7;      // 128-pixel tile
  u32* Vl32 = (u32*)Vl;
  const float QSC = 0.20412414523193154f * 1.4426950408889634f;  // 24^-0.5 * log2(e)
  if (t < 128) {
    int p = p0 + t;
    float qv[24], kv[24];
    float sq = 0.f, sk = 0.f;
    #pragma unroll
    for (int d = 0; d < 24; ++d) {
      qv[d] = qkv[(size_t)(h * 24 + d) * 4096 + p];
      sq = fmaf(qv[d], qv[d], sq);
    }
    #pragma unroll
    for (int d = 0; d < 24; ++d) {
      kv[d] = qkv[(size_t)(192 + h * 24 + d) * 4096 + p];
      sk = fmaf(kv[d], kv[d], sk);
    }
    float iq = QSC / fmaxf(sqrtf(sq), 1e-12f);  // F.normalize: x / max(||x||, eps)
    float ik = 1.0f / fmaxf(sqrtf(sk), 1e-12f);
    u32* qrow = Ql + t * 17;
    u32* krow = Kl + t * 17;
    #pragma unroll
    for (int j = 0; j < 12; ++j) {
      qrow[j] = ((u32)f2bf(qv[2 * j + 1] * iq) << 16) | f2bf(qv[2 * j] * iq);
      krow[j] = ((u32)f2bf(kv[2 * j + 1] * ik) << 16) | f2bf(kv[2 * j] * ik);
    }
    #pragma unroll
    for (int j = 12; j < 16; ++j) { qrow[j] = 0; krow[j] = 0; }
  } else {
    int tl = t - 128;
    int p = p0 + tl;
    // A-frag key permutation (see header comment)
    int kp = (tl & ~63) | (tl & 32) | (((tl >> 2) & 3) << 3) |
             (((tl >> 4) & 1) << 2) | (tl & 3);
    #pragma unroll
    for (int d = 0; d < 24; ++d)
      Vl[d * 128 + kp] = f2bf(qkv[(size_t)(384 + h * 24 + d) * 4096 + p]);
    Vl[24 * 128 + kp] = 0x3F80;  // bf16 1.0
  }
  for (int i = t; i < 7 * 64; i += 256) Vl32[25 * 64 + i] = 0;  // zero d=25..31
  __syncthreads();
  size_t base = ((size_t)(h << 12) + p0) * 16;
  for (int i = t; i < 2048; i += 256) {
    u32 li = (i >> 4) * 17 + (i & 15);
    Qh32[base + i] = Ql[li];
    Kh32[base + i] = Kl[li];
  }
  for (int i = t; i < 2048; i += 256) {
    int d = i >> 6, c = i & 63;
    Vt32[(((size_t)(h * 32 + d)) << 11) + (p0 >> 1) + c] = Vl32[d * 64 + c];
  }
}

// exp2 each element of two f32x4 (S^T regs r=0..3 = keys quad*4+r), truncate to
// bf16, pack into a PV A-fragment (slots j=0..3 from a, j=4..7 from b).
__device__ __forceinline__ bf16x8 pexp(f32x4 a, f32x4 b) {
  union { u32 u[4]; bf16x8 v; } x;
  u32 a0 = __float_as_uint(__builtin_amdgcn_exp2f(a[0]));
  u32 a1 = __float_as_uint(__builtin_amdgcn_exp2f(a[1]));
  u32 a2 = __float_as_uint(__builtin_amdgcn_exp2f(a[2]));
  u32 a3 = __float_as_uint(__builtin_amdgcn_exp2f(a[3]));
  u32 b0 = __float_as_uint(__builtin_amdgcn_exp2f(b[0]));
  u32 b1 = __float_as_uint(__builtin_amdgcn_exp2f(b[1]));
  u32 b2 = __float_as_uint(__builtin_amdgcn_exp2f(b[2]));
  u32 b3 = __float_as_uint(__builtin_amdgcn_exp2f(b[3]));
  x.u[0] = __builtin_amdgcn_perm(a1, a0, 0x07060302u);
  x.u[1] = __builtin_amdgcn_perm(a3, a2, 0x07060302u);
  x.u[2] = __builtin_amdgcn_perm(b1, b0, 0x07060302u);
  x.u[3] = __builtin_amdgcn_perm(b3, b2, 0x07060302u);
  return x.v;
}

// ---- K4: flash attention, register-resident P, 4 Q-frags/wave (64 q), zero
// global intermediates, K double-buffered (R14/R16 core, frozen). NEW epilogue:
// emits bf16 Pt[4096][192] (pixel-major) via LDS staging + coalesced u32 stores
// so the proj GEMM can run on MFMA (mqkv reused).
__global__ __launch_bounds__(512, 4) void attn(const u16* __restrict__ Qh,
                                               const u16* __restrict__ Kh,
                                               const u16* __restrict__ Vt,
                                               u16* __restrict__ Pt) {
  __shared__ float Sf[8 * 64 * 28];  // 57344 B epilogue staging
  __shared__ u16 Pb[64 * 24];        // 3072 B bf16 out staging
  int tid = threadIdx.x;
  int wave = tid >> 6, lane = tid & 63;
  int lo = lane & 15, hi = lane >> 4;
  int b = blockIdx.x;
  int head = b & 7;              // head == XCD (round-robin) -> K/V L2-resident
  int q0 = (b >> 3) << 6;        // 64 queries per block

  const u16* Kb = Kh + ((size_t)head << 17);
  const u16* Vb = Vt + ((size_t)head << 17);

  size_t qrow = (size_t)(head << 12) + q0 + lo;
  bf16x8 qf[4];
  #pragma unroll
  for (int f = 0; f < 4; ++f)
    qf[f] = *(const bf16x8*)(Qh + ((qrow + f * 16) << 5) + hi * 8);

  f32x4 zz = {0.f, 0.f, 0.f, 0.f};
  f32x4 oA[4], oB[4];
  #pragma unroll
  for (int f = 0; f < 4; ++f) { oA[f] = zz; oB[f] = zz; }

  int kbase = wave << 9;                        // 512 keys per wave

  bf16x8 kf[2][4];
  #pragma unroll
  for (int j = 0; j < 4; ++j)
    kf[0][j] = *(const bf16x8*)(Kb + (((size_t)(kbase + j * 16 + lo)) << 5) + hi * 8);

  #pragma unroll
  for (int it = 0; it < 8; ++it) {              // 8 tiles of 64 keys
    int cur = it & 1;
    int k0 = kbase + it * 64;
    bf16x8 vf[4];
    vf[0] = *(const bf16x8*)(Vb + (((size_t)(lo)) << 12) + k0 + hi * 8);
    vf[1] = *(const bf16x8*)(Vb + (((size_t)(16 + lo)) << 12) + k0 + hi * 8);
    vf[2] = *(const bf16x8*)(Vb + (((size_t)(lo)) << 12) + k0 + 32 + hi * 8);
    vf[3] = *(const bf16x8*)(Vb + (((size_t)(16 + lo)) << 12) + k0 + 32 + hi * 8);
    if (it < 7) {                               // prefetch next tile's K
      #pragma unroll
      for (int j = 0; j < 4; ++j)
        kf[cur ^ 1][j] = *(const bf16x8*)(Kb + (((size_t)(k0 + 64 + j * 16 + lo)) << 5) + hi * 8);
    }
    #pragma unroll
    for (int f = 0; f < 4; ++f) {
      f32x4 t0 = __builtin_amdgcn_mfma_f32_16x16x32_bf16(kf[cur][0], qf[f], zz, 0, 0, 0);
      f32x4 t1 = __builtin_amdgcn_mfma_f32_16x16x32_bf16(kf[cur][1], qf[f], zz, 0, 0, 0);
      f32x4 t2 = __builtin_amdgcn_mfma_f32_16x16x32_bf16(kf[cur][2], qf[f], zz, 0, 0, 0);
      f32x4 t3 = __builtin_amdgcn_mfma_f32_16x16x32_bf16(kf[cur][3], qf[f], zz, 0, 0, 0);
      bf16x8 a0 = pexp(t0, t1);
      bf16x8 a1 = pexp(t2, t3);
      oA[f] = __builtin_amdgcn_mfma_f32_16x16x32_bf16(a0, vf[0], oA[f], 0, 0, 0);
      oB[f] = __builtin_amdgcn_mfma_f32_16x16x32_bf16(a0, vf[1], oB[f], 0, 0, 0);
      oA[f] = __builtin_amdgcn_mfma_f32_16x16x32_bf16(a1, vf[2], oA[f], 0, 0, 0);
      oB[f] = __builtin_amdgcn_mfma_f32_16x16x32_bf16(a1, vf[3], oB[f], 0, 0, 0);
    }
  }

  // phase 1: stage fp32 C-layout (num cols 0..23, den col 24) into OWN strip.
  int sb = wave * (64 * 28);
  #pragma unroll
  for (int f = 0; f < 4; ++f) {
    #pragma unroll
    for (int r = 0; r < 4; ++r) {
      int row = f * 16 + hi * 4 + r;
      Sf[sb + row * 28 + lo] = oA[f][r];
      if (lo < 8) Sf[sb + row * 28 + 16 + lo] = oB[f][r];
      if (lo == 8) Sf[sb + row * 28 + 24] = oB[f][r];   // ones-row = denominator
    }
  }
  __syncthreads();
  // phase 2: reduce the 8 K-eighths, normalize, stage bf16 per-pixel rows.
  int q = tid & 63;              // local query row
  int d0 = tid >> 6;             // 0..7
  int base0 = q * 28;
  const int SS = 64 * 28;
  float den = 0.f;
  #pragma unroll
  for (int s = 0; s < 8; ++s) den += Sf[base0 + s * SS + 24];
  float inv = 1.0f / den;
  #pragma unroll
  for (int dp = 0; dp < 3; ++dp) {
    int dd = dp * 8 + d0;
    float v = 0.f;
    #pragma unroll
    for (int s = 0; s < 8; ++s) v += Sf[base0 + s * SS + dd];
    Pb[q * 24 + dd] = f2bf(v * inv);
  }
  __syncthreads();
  // phase 3: coalesced u32 stores of this block's [64 px][12 u32] strip at
  // column offset head*24 bf16 of Pt[4096][192].
  const u32* Pb32 = (const u32*)Pb;
  u32* Pt32 = (u32*)Pt;
  for (int i = tid; i < 768; i += 512) {
    int qq = i / 12, j = i - qq * 12;
    Pt32[(size_t)(q0 + qq) * 96 + head * 12 + j] = Pb32[qq * 12 + j];
  }
}

extern "C" void kernel_launch(void* const* d_in, const int* in_sizes, int n_in,
                              void* d_out, int out_size, void* d_ws, size_t ws_size,
                              hipStream_t stream) {
  const float* x      = (const float*)d_in[0];  // [192][4096]
  const float* w_qkv  = (const float*)d_in[1];  // [576][192]
  const float* w_dw   = (const float*)d_in[2];  // [576][9]
  const float* w_proj = (const float*)d_in[3];  // [192][192]
  float* out = (float*)d_out;                   // [192][4096] fp32

  char* ws = (char*)d_ws;
  float* qkv    = (float*)(ws);                 // 9437184  (dead after dwconv3)
  float* qkvd   = (float*)(ws + 9437184);       // 9437184  (dead after nvpack)
  u16*   Qh     = (u16*)  (ws + 18874368);      // 2097152
  u16*   Kh     = (u16*)  (ws + 20971520);      // 2097152
  u16*   Vt     = (u16*)  (ws + 23068672);      // 2097152  (end 25165824)
  u16*   Xt     = (u16*)  (ws + 25165824);      // 1572864  (bf16 X^T)
  u16*   Wb     = (u16*)  (ws + 26738688);      // 221184
  u16*   Wpb    = (u16*)  (ws + 26959872);      // 73728    (end 27033600)
  u16*   Pt     = (u16*)  (ws + 13107200);      // 1572864  (bf16 attn-out^T, inside dead qkvd)

  // prep: X transpose->bf16 (128) + w_qkv->bf16 (54) + w_proj->bf16 (18)
  prep<<<dim3(200), 256, 0, stream>>>(x, w_qkv, w_proj, Xt, Wb, Wpb);
  // qkv GEMM on MFMA: grid (32 n-tiles, 18 m-tiles)
  mqkv<<<dim3(32, 18), 256, 0, stream>>>(Wb, Xt, qkv);
  dwconv3<<<dim3(9216), 256, 0, stream>>>(qkv, w_dw, qkvd);
  nvpack<<<dim3(256), 256, 0, stream>>>(qkvd, (u32*)Qh, (u32*)Kh, (u32*)Vt);
  // 512 blocks x 512 threads; 4 q-frags/wave, register-resident P, K dbuf;
  // emits bf16 Pt for the MFMA proj
  attn<<<dim3(512), 512, 0, stream>>>(Qh, Kh, Vt, Pt);
  // proj GEMM on MFMA (mqkv reused): grid (32 n-tiles, 6 m-tiles)
  mqkv<<<dim3(32, 6), 256, 0, stream>>>(Wpb, Pt, out);
}

// Round 20
// 126.179 us; speedup vs baseline: 1.2853x; 1.0210x over previous
//
#include <hip/hip_runtime.h>

typedef unsigned short u16;
typedef unsigned int u32;
typedef short bf16x8 __attribute__((ext_vector_type(8)));
typedef float f32x4 __attribute__((ext_vector_type(4)));

// float -> bf16 bits, round-to-nearest-even (inputs never NaN here)
__device__ __forceinline__ u16 f2bf(float f) {
  union { float f; unsigned int u; } a; a.f = f;
  unsigned int r = a.u + 0x7FFFu + ((a.u >> 16) & 1u);
  return (u16)(r >> 16);
}
// bf16 bits -> float (exact)
__device__ __forceinline__ float bf2f(u16 b) {
  return __uint_as_float(((u32)b) << 16);
}

// ---- K0: prep. Blocks 0..127: transpose X [192][4096] fp32 -> Xt [4096][192]
// bf16 (32-px tiles via LDS). Blocks 128..181: w_qkv -> bf16. Blocks 182..199:
// w_proj -> bf16. ----
__global__ __launch_bounds__(256) void prep(const float* __restrict__ X,
                                            const float* __restrict__ W,
                                            const float* __restrict__ Wp,
                                            u16* __restrict__ Xt,
                                            u16* __restrict__ Wb,
                                            u16* __restrict__ Wpb) {
  int b = blockIdx.x;
  int t = threadIdx.x;
  if (b < 128) {
    __shared__ float Xl[192 * 33];   // 25344 B, +1 pad
    int p0 = b << 5;
    int px = t & 31, cs = t >> 5;    // 8 c-groups
    #pragma unroll
    for (int i = 0; i < 24; ++i) {
      int c = cs * 24 + i;
      Xl[c * 33 + px] = X[(size_t)c * 4096 + p0 + px];
    }
    __syncthreads();
    int pxo = t >> 3, j0 = (t & 7) * 12;     // 32 px x 96 u32 rows
    u32* Xt32 = (u32*)Xt;
    #pragma unroll
    for (int jj = 0; jj < 12; ++jj) {
      int j = j0 + jj;
      u32 v = ((u32)f2bf(Xl[(2 * j + 1) * 33 + pxo]) << 16) |
              f2bf(Xl[(2 * j) * 33 + pxo]);
      Xt32[(size_t)(p0 + pxo) * 96 + j] = v;
    }
  } else if (b < 182) {
    int idx = (b - 128) * 2048 + t * 8;      // 54 blocks x 2048 = 110592
    #pragma unroll
    for (int i = 0; i < 8; ++i) Wb[idx + i] = f2bf(W[idx + i]);
  } else {
    int idx = (b - 182) * 2048 + t * 8;      // 18 blocks x 2048 = 36864
    #pragma unroll
    for (int i = 0; i < 8; ++i) Wpb[idx + i] = f2bf(Wp[idx + i]);
  }
}

// ---- K1 (and K5): MFMA GEMM. Y[M][4096] = A[M][192] x B[4096][192] (bf16 in,
// K=192 = 6 k-steps). Wave tile 32m x 32n (2x2 frags); block = 4 waves = 32m x
// 128n; grid (32, M/32). B16 output: bf16 via wave-private LDS re-tile +
// coalesced u32 stores (direct u16 scatter would half-line-amplify, R6 lesson);
// else fp32 direct. ----
template <bool B16>
__global__ __launch_bounds__(256) void mqkv(const u16* __restrict__ Wb,
                                            const u16* __restrict__ Xt,
                                            void* __restrict__ Yv) {
  __shared__ u16 Sl[4][32 * 32];   // 8 KB, wave-private strips
  int tid = threadIdx.x;
  int wave = tid >> 6, lane = tid & 63;
  int lo = lane & 15, hi = lane >> 4;
  int m0 = blockIdx.y << 5;
  int n0 = (blockIdx.x << 7) + (wave << 5);
  f32x4 zz = {0.f, 0.f, 0.f, 0.f};
  f32x4 acc00 = zz, acc01 = zz, acc10 = zz, acc11 = zz;
  #pragma unroll
  for (int k0 = 0; k0 < 192; k0 += 32) {
    bf16x8 a0 = *(const bf16x8*)(Wb + (size_t)(m0 + lo) * 192 + k0 + hi * 8);
    bf16x8 a1 = *(const bf16x8*)(Wb + (size_t)(m0 + 16 + lo) * 192 + k0 + hi * 8);
    bf16x8 b0 = *(const bf16x8*)(Xt + (size_t)(n0 + lo) * 192 + k0 + hi * 8);
    bf16x8 b1 = *(const bf16x8*)(Xt + (size_t)(n0 + 16 + lo) * 192 + k0 + hi * 8);
    acc00 = __builtin_amdgcn_mfma_f32_16x16x32_bf16(a0, b0, acc00, 0, 0, 0);
    acc01 = __builtin_amdgcn_mfma_f32_16x16x32_bf16(a0, b1, acc01, 0, 0, 0);
    acc10 = __builtin_amdgcn_mfma_f32_16x16x32_bf16(a1, b0, acc10, 0, 0, 0);
    acc11 = __builtin_amdgcn_mfma_f32_16x16x32_bf16(a1, b1, acc11, 0, 0, 0);
  }
  if (B16) {
    u16* S = Sl[wave];
    #pragma unroll
    for (int r = 0; r < 4; ++r) {
      S[(hi * 4 + r) * 32 + lo] = f2bf(acc00[r]);
      S[(hi * 4 + r) * 32 + 16 + lo] = f2bf(acc01[r]);
      S[(16 + hi * 4 + r) * 32 + lo] = f2bf(acc10[r]);
      S[(16 + hi * 4 + r) * 32 + 16 + lo] = f2bf(acc11[r]);
    }
    // wave-private LDS is in-order: no barrier. Coalesced u32 stores.
    const u32* S32 = (const u32*)S;
    u32* Y32 = (u32*)Yv;            // bf16 Y, row stride 2048 u32
    #pragma unroll
    for (int i = lane; i < 512; i += 64) {
      int row = i >> 4, j = i & 15;
      Y32[(size_t)(m0 + row) * 2048 + (n0 >> 1) + j] = S32[row * 16 + j];
    }
  } else {
    float* Y = (float*)Yv;
    #pragma unroll
    for (int r = 0; r < 4; ++r) {
      Y[(size_t)(m0 + hi * 4 + r) * 4096 + n0 + lo] = acc00[r];
      Y[(size_t)(m0 + hi * 4 + r) * 4096 + n0 + 16 + lo] = acc01[r];
      Y[(size_t)(m0 + 16 + hi * 4 + r) * 4096 + n0 + lo] = acc10[r];
      Y[(size_t)(m0 + 16 + hi * 4 + r) * 4096 + n0 + 16 + lo] = acc11[r];
    }
  }
}

// ---- K2: depthwise 3x3, pad=1, on [576][64][64], bf16 in/out (fp32 math,
// identical fmaf order; one rounding on store). 1 ch/thread, 9216 blocks. ----
__global__ __launch_bounds__(256) void dwconv3(const u16* __restrict__ in,
                                               const float* __restrict__ w,
                                               u16* __restrict__ out) {
  int idx = blockIdx.x * 256 + threadIdx.x;  // c*4096 + p
  int c = idx >> 12;
  int p = idx & 4095;
  int y = p >> 6, x = p & 63;
  const float* wc = w + c * 9;
  const u16* ic = in + (size_t)c * 4096;
  float s = 0.f;
  #pragma unroll
  for (int i = 0; i < 3; ++i) {
    int yy = y + i - 1;
    if ((unsigned)yy >= 64u) continue;
    #pragma unroll
    for (int j = 0; j < 3; ++j) {
      int xx = x + j - 1;
      if ((unsigned)xx >= 64u) continue;
      s = fmaf(wc[i * 3 + j], bf2f(ic[yy * 64 + xx]), s);
    }
  }
  out[idx] = f2bf(s);
}

// ---- K3: fused normalize+pack (bf16 input). 256 blocks; per block: 128 px of
// one head. Threads 0..127: Q+K norm+pack ([h][p][32] bf16). 128..255: V pack
// with the A-frag key permutation. Row d==24 = ones -> denominator. ----
__global__ __launch_bounds__(256) void nvpack(const u16* __restrict__ qkv,
                                              u32* __restrict__ Qh32,
                                              u32* __restrict__ Kh32,
                                              u32* __restrict__ Vt32) {
  __shared__ u32 Ql[128 * 17];
  __shared__ u32 Kl[128 * 17];
  __shared__ u16 Vl[32 * 128];
  int t = threadIdx.x;
  int bid = blockIdx.x;          // 256 blocks
  int h = bid >> 5;
  int p0 = (bid & 31) << 7;      // 128-pixel tile
  u32* Vl32 = (u32*)Vl;
  const float QSC = 0.20412414523193154f * 1.4426950408889634f;  // 24^-0.5 * log2(e)
  if (t < 128) {
    int p = p0 + t;
    float qv[24], kv[24];
    float sq = 0.f, sk = 0.f;
    #pragma unroll
    for (int d = 0; d < 24; ++d) {
      qv[d] = bf2f(qkv[(size_t)(h * 24 + d) * 4096 + p]);
      sq = fmaf(qv[d], qv[d], sq);
    }
    #pragma unroll
    for (int d = 0; d < 24; ++d) {
      kv[d] = bf2f(qkv[(size_t)(192 + h * 24 + d) * 4096 + p]);
      sk = fmaf(kv[d], kv[d], sk);
    }
    float iq = QSC / fmaxf(sqrtf(sq), 1e-12f);  // F.normalize semantics
    float ik = 1.0f / fmaxf(sqrtf(sk), 1e-12f);
    u32* qrow = Ql + t * 17;
    u32* krow = Kl + t * 17;
    #pragma unroll
    for (int j = 0; j < 12; ++j) {
      qrow[j] = ((u32)f2bf(qv[2 * j + 1] * iq) << 16) | f2bf(qv[2 * j] * iq);
      krow[j] = ((u32)f2bf(kv[2 * j + 1] * ik) << 16) | f2bf(kv[2 * j] * ik);
    }
    #pragma unroll
    for (int j = 12; j < 16; ++j) { qrow[j] = 0; krow[j] = 0; }
  } else {
    int tl = t - 128;
    int p = p0 + tl;
    // A-frag key permutation
    int kp = (tl & ~63) | (tl & 32) | (((tl >> 2) & 3) << 3) |
             (((tl >> 4) & 1) << 2) | (tl & 3);
    #pragma unroll
    for (int d = 0; d < 24; ++d)
      Vl[d * 128 + kp] = qkv[(size_t)(384 + h * 24 + d) * 4096 + p];  // bf16 passthrough
    Vl[24 * 128 + kp] = 0x3F80;  // bf16 1.0
  }
  for (int i = t; i < 7 * 64; i += 256) Vl32[25 * 64 + i] = 0;  // zero d=25..31
  __syncthreads();
  size_t base = ((size_t)(h << 12) + p0) * 16;
  for (int i = t; i < 2048; i += 256) {
    u32 li = (i >> 4) * 17 + (i & 15);
    Qh32[base + i] = Ql[li];
    Kh32[base + i] = Kl[li];
  }
  for (int i = t; i < 2048; i += 256) {
    int d = i >> 6, c = i & 63;
    Vt32[(((size_t)(h * 32 + d)) << 11) + (p0 >> 1) + c] = Vl32[d * 64 + c];
  }
}

// exp2 each element of two f32x4 (S^T regs r=0..3 = keys quad*4+r), truncate to
// bf16, pack into a PV A-fragment (slots j=0..3 from a, j=4..7 from b).
__device__ __forceinline__ bf16x8 pexp(f32x4 a, f32x4 b) {
  union { u32 u[4]; bf16x8 v; } x;
  u32 a0 = __float_as_uint(__builtin_amdgcn_exp2f(a[0]));
  u32 a1 = __float_as_uint(__builtin_amdgcn_exp2f(a[1]));
  u32 a2 = __float_as_uint(__builtin_amdgcn_exp2f(a[2]));
  u32 a3 = __float_as_uint(__builtin_amdgcn_exp2f(a[3]));
  u32 b0 = __float_as_uint(__builtin_amdgcn_exp2f(b[0]));
  u32 b1 = __float_as_uint(__builtin_amdgcn_exp2f(b[1]));
  u32 b2 = __float_as_uint(__builtin_amdgcn_exp2f(b[2]));
  u32 b3 = __float_as_uint(__builtin_amdgcn_exp2f(b[3]));
  x.u[0] = __builtin_amdgcn_perm(a1, a0, 0x07060302u);
  x.u[1] = __builtin_amdgcn_perm(a3, a2, 0x07060302u);
  x.u[2] = __builtin_amdgcn_perm(b1, b0, 0x07060302u);
  x.u[3] = __builtin_amdgcn_perm(b3, b2, 0x07060302u);
  return x.v;
}

// ---- K4: flash attention, register-resident P, 4 Q-frags/wave (64 q), zero
// global intermediates, K double-buffered (frozen core). Epilogue emits bf16
// Pt[4096][192] for the MFMA proj. ----
__global__ __launch_bounds__(512, 4) void attn(const u16* __restrict__ Qh,
                                               const u16* __restrict__ Kh,
                                               const u16* __restrict__ Vt,
                                               u16* __restrict__ Pt) {
  __shared__ float Sf[8 * 64 * 28];  // 57344 B epilogue staging
  __shared__ u16 Pb[64 * 24];        // 3072 B bf16 out staging
  int tid = threadIdx.x;
  int wave = tid >> 6, lane = tid & 63;
  int lo = lane & 15, hi = lane >> 4;
  int b = blockIdx.x;
  int head = b & 7;              // head == XCD (round-robin) -> K/V L2-resident
  int q0 = (b >> 3) << 6;        // 64 queries per block

  const u16* Kb = Kh + ((size_t)head << 17);
  const u16* Vb = Vt + ((size_t)head << 17);

  size_t qrow = (size_t)(head << 12) + q0 + lo;
  bf16x8 qf[4];
  #pragma unroll
  for (int f = 0; f < 4; ++f)
    qf[f] = *(const bf16x8*)(Qh + ((qrow + f * 16) << 5) + hi * 8);

  f32x4 zz = {0.f, 0.f, 0.f, 0.f};
  f32x4 oA[4], oB[4];
  #pragma unroll
  for (int f = 0; f < 4; ++f) { oA[f] = zz; oB[f] = zz; }

  int kbase = wave << 9;                        // 512 keys per wave

  bf16x8 kf[2][4];
  #pragma unroll
  for (int j = 0; j < 4; ++j)
    kf[0][j] = *(const bf16x8*)(Kb + (((size_t)(kbase + j * 16 + lo)) << 5) + hi * 8);

  #pragma unroll
  for (int it = 0; it < 8; ++it) {              // 8 tiles of 64 keys
    int cur = it & 1;
    int k0 = kbase + it * 64;
    bf16x8 vf[4];
    vf[0] = *(const bf16x8*)(Vb + (((size_t)(lo)) << 12) + k0 + hi * 8);
    vf[1] = *(const bf16x8*)(Vb + (((size_t)(16 + lo)) << 12) + k0 + hi * 8);
    vf[2] = *(const bf16x8*)(Vb + (((size_t)(lo)) << 12) + k0 + 32 + hi * 8);
    vf[3] = *(const bf16x8*)(Vb + (((size_t)(16 + lo)) << 12) + k0 + 32 + hi * 8);
    if (it < 7) {                               // prefetch next tile's K
      #pragma unroll
      for (int j = 0; j < 4; ++j)
        kf[cur ^ 1][j] = *(const bf16x8*)(Kb + (((size_t)(k0 + 64 + j * 16 + lo)) << 5) + hi * 8);
    }
    #pragma unroll
    for (int f = 0; f < 4; ++f) {
      f32x4 t0 = __builtin_amdgcn_mfma_f32_16x16x32_bf16(kf[cur][0], qf[f], zz, 0, 0, 0);
      f32x4 t1 = __builtin_amdgcn_mfma_f32_16x16x32_bf16(kf[cur][1], qf[f], zz, 0, 0, 0);
      f32x4 t2 = __builtin_amdgcn_mfma_f32_16x16x32_bf16(kf[cur][2], qf[f], zz, 0, 0, 0);
      f32x4 t3 = __builtin_amdgcn_mfma_f32_16x16x32_bf16(kf[cur][3], qf[f], zz, 0, 0, 0);
      bf16x8 a0 = pexp(t0, t1);
      bf16x8 a1 = pexp(t2, t3);
      oA[f] = __builtin_amdgcn_mfma_f32_16x16x32_bf16(a0, vf[0], oA[f], 0, 0, 0);
      oB[f] = __builtin_amdgcn_mfma_f32_16x16x32_bf16(a0, vf[1], oB[f], 0, 0, 0);
      oA[f] = __builtin_amdgcn_mfma_f32_16x16x32_bf16(a1, vf[2], oA[f], 0, 0, 0);
      oB[f] = __builtin_amdgcn_mfma_f32_16x16x32_bf16(a1, vf[3], oB[f], 0, 0, 0);
    }
  }

  // phase 1: stage fp32 C-layout (num cols 0..23, den col 24) into OWN strip.
  int sb = wave * (64 * 28);
  #pragma unroll
  for (int f = 0; f < 4; ++f) {
    #pragma unroll
    for (int r = 0; r < 4; ++r) {
      int row = f * 16 + hi * 4 + r;
      Sf[sb + row * 28 + lo] = oA[f][r];
      if (lo < 8) Sf[sb + row * 28 + 16 + lo] = oB[f][r];
      if (lo == 8) Sf[sb + row * 28 + 24] = oB[f][r];   // ones-row = denominator
    }
  }
  __syncthreads();
  // phase 2: reduce the 8 K-eighths, normalize, stage bf16 per-pixel rows.
  int q = tid & 63;              // local query row
  int d0 = tid >> 6;             // 0..7
  int base0 = q * 28;
  const int SS = 64 * 28;
  float den = 0.f;
  #pragma unroll
  for (int s = 0; s < 8; ++s) den += Sf[base0 + s * SS + 24];
  float inv = 1.0f / den;
  #pragma unroll
  for (int dp = 0; dp < 3; ++dp) {
    int dd = dp * 8 + d0;
    float v = 0.f;
    #pragma unroll
    for (int s = 0; s < 8; ++s) v += Sf[base0 + s * SS + dd];
    Pb[q * 24 + dd] = f2bf(v * inv);
  }
  __syncthreads();
  // phase 3: coalesced u32 stores of this block's [64 px][12 u32] strip.
  const u32* Pb32 = (const u32*)Pb;
  u32* Pt32 = (u32*)Pt;
  for (int i = tid; i < 768; i += 512) {
    int qq = i / 12, j = i - qq * 12;
    Pt32[(size_t)(q0 + qq) * 96 + head * 12 + j] = Pb32[qq * 12 + j];
  }
}

extern "C" void kernel_launch(void* const* d_in, const int* in_sizes, int n_in,
                              void* d_out, int out_size, void* d_ws, size_t ws_size,
                              hipStream_t stream) {
  const float* x      = (const float*)d_in[0];  // [192][4096]
  const float* w_qkv  = (const float*)d_in[1];  // [576][192]
  const float* w_dw   = (const float*)d_in[2];  // [576][9]
  const float* w_proj = (const float*)d_in[3];  // [192][192]
  float* out = (float*)d_out;                   // [192][4096] fp32

  char* ws = (char*)d_ws;
  u16*   qkv    = (u16*)  (ws);                 // 4718592 bf16 (dead after dwconv3)
  u16*   qkvd   = (u16*)  (ws + 4718592);       // 4718592 bf16 (dead after nvpack)
  u16*   Qh     = (u16*)  (ws + 18874368);      // 2097152
  u16*   Kh     = (u16*)  (ws + 20971520);      // 2097152
  u16*   Vt     = (u16*)  (ws + 23068672);      // 2097152  (end 25165824)
  u16*   Xt     = (u16*)  (ws + 25165824);      // 1572864  (bf16 X^T)
  u16*   Wb     = (u16*)  (ws + 26738688);      // 221184
  u16*   Wpb    = (u16*)  (ws + 26959872);      // 73728    (end 27033600)
  u16*   Pt     = (u16*)  (ws + 13107200);      // 1572864  (bf16 attn-out^T)

  // prep: X transpose->bf16 (128) + w_qkv->bf16 (54) + w_proj->bf16 (18)
  prep<<<dim3(200), 256, 0, stream>>>(x, w_qkv, w_proj, Xt, Wb, Wpb);
  // qkv GEMM on MFMA, bf16 out: grid (32 n-tiles, 18 m-tiles)
  mqkv<true><<<dim3(32, 18), 256, 0, stream>>>(Wb, Xt, qkv);
  dwconv3<<<dim3(9216), 256, 0, stream>>>(qkv, w_dw, qkvd);
  nvpack<<<dim3(256), 256, 0, stream>>>(qkvd, (u32*)Qh, (u32*)Kh, (u32*)Vt);
  // 512 blocks x 512 threads; 4 q-frags/wave, register-resident P, K dbuf
  attn<<<dim3(512), 512, 0, stream>>>(Qh, Kh, Vt, Pt);
  // proj GEMM on MFMA, fp32 out: grid (32 n-tiles, 6 m-tiles)
  mqkv<false><<<dim3(32, 6), 256, 0, stream>>>(Wpb, Pt, out);
}

// Round 21
// 125.124 us; speedup vs baseline: 1.2962x; 1.0084x over previous
//
#include <hip/hip_runtime.h>

typedef unsigned short u16;
typedef unsigned int u32;
typedef short bf16x8 __attribute__((ext_vector_type(8)));
typedef float f32x4 __attribute__((ext_vector_type(4)));

// float -> bf16 bits, round-to-nearest-even (inputs never NaN here)
__device__ __forceinline__ u16 f2bf(float f) {
  union { float f; unsigned int u; } a; a.f = f;
  unsigned int r = a.u + 0x7FFFu + ((a.u >> 16) & 1u);
  return (u16)(r >> 16);
}
// bf16 bits -> float (exact)
__device__ __forceinline__ float bf2f(u16 b) {
  return __uint_as_float(((u32)b) << 16);
}

// ---- K0: prep. Blocks 0..127: transpose X [192][4096] fp32 -> Xt [4096][192]
// bf16 (32-px tiles via LDS). Blocks 128..181: w_qkv -> bf16. Blocks 182..199:
// w_proj -> bf16. ----
__global__ __launch_bounds__(256) void prep(const float* __restrict__ X,
                                            const float* __restrict__ W,
                                            const float* __restrict__ Wp,
                                            u16* __restrict__ Xt,
                                            u16* __restrict__ Wb,
                                            u16* __restrict__ Wpb) {
  int b = blockIdx.x;
  int t = threadIdx.x;
  if (b < 128) {
    __shared__ float Xl[192 * 33];   // 25344 B, +1 pad
    int p0 = b << 5;
    int px = t & 31, cs = t >> 5;    // 8 c-groups
    #pragma unroll
    for (int i = 0; i < 24; ++i) {
      int c = cs * 24 + i;
      Xl[c * 33 + px] = X[(size_t)c * 4096 + p0 + px];
    }
    __syncthreads();
    int pxo = t >> 3, j0 = (t & 7) * 12;     // 32 px x 96 u32 rows
    u32* Xt32 = (u32*)Xt;
    #pragma unroll
    for (int jj = 0; jj < 12; ++jj) {
      int j = j0 + jj;
      u32 v = ((u32)f2bf(Xl[(2 * j + 1) * 33 + pxo]) << 16) |
              f2bf(Xl[(2 * j) * 33 + pxo]);
      Xt32[(size_t)(p0 + pxo) * 96 + j] = v;
    }
  } else if (b < 182) {
    int idx = (b - 128) * 2048 + t * 8;      // 54 blocks x 2048 = 110592
    #pragma unroll
    for (int i = 0; i < 8; ++i) Wb[idx + i] = f2bf(W[idx + i]);
  } else {
    int idx = (b - 182) * 2048 + t * 8;      // 18 blocks x 2048 = 36864
    #pragma unroll
    for (int i = 0; i < 8; ++i) Wpb[idx + i] = f2bf(Wp[idx + i]);
  }
}

// ---- K1 (and K5): MFMA GEMM. Y[M][4096] = A[M][192] x B[4096][192] (bf16 in,
// K=192 = 6 k-steps). Wave tile 32m x 32n (2x2 frags); block = 4 waves = 32m x
// 128n; grid (32, M/32). B16 output: bf16 via wave-private LDS re-tile +
// coalesced u32 stores; else fp32 direct. ----
template <bool B16>
__global__ __launch_bounds__(256) void mqkv(const u16* __restrict__ Wb,
                                            const u16* __restrict__ Xt,
                                            void* __restrict__ Yv) {
  __shared__ u16 Sl[4][32 * 32];   // 8 KB, wave-private strips
  int tid = threadIdx.x;
  int wave = tid >> 6, lane = tid & 63;
  int lo = lane & 15, hi = lane >> 4;
  int m0 = blockIdx.y << 5;
  int n0 = (blockIdx.x << 7) + (wave << 5);
  f32x4 zz = {0.f, 0.f, 0.f, 0.f};
  f32x4 acc00 = zz, acc01 = zz, acc10 = zz, acc11 = zz;
  #pragma unroll
  for (int k0 = 0; k0 < 192; k0 += 32) {
    bf16x8 a0 = *(const bf16x8*)(Wb + (size_t)(m0 + lo) * 192 + k0 + hi * 8);
    bf16x8 a1 = *(const bf16x8*)(Wb + (size_t)(m0 + 16 + lo) * 192 + k0 + hi * 8);
    bf16x8 b0 = *(const bf16x8*)(Xt + (size_t)(n0 + lo) * 192 + k0 + hi * 8);
    bf16x8 b1 = *(const bf16x8*)(Xt + (size_t)(n0 + 16 + lo) * 192 + k0 + hi * 8);
    acc00 = __builtin_amdgcn_mfma_f32_16x16x32_bf16(a0, b0, acc00, 0, 0, 0);
    acc01 = __builtin_amdgcn_mfma_f32_16x16x32_bf16(a0, b1, acc01, 0, 0, 0);
    acc10 = __builtin_amdgcn_mfma_f32_16x16x32_bf16(a1, b0, acc10, 0, 0, 0);
    acc11 = __builtin_amdgcn_mfma_f32_16x16x32_bf16(a1, b1, acc11, 0, 0, 0);
  }
  if (B16) {
    u16* S = Sl[wave];
    #pragma unroll
    for (int r = 0; r < 4; ++r) {
      S[(hi * 4 + r) * 32 + lo] = f2bf(acc00[r]);
      S[(hi * 4 + r) * 32 + 16 + lo] = f2bf(acc01[r]);
      S[(16 + hi * 4 + r) * 32 + lo] = f2bf(acc10[r]);
      S[(16 + hi * 4 + r) * 32 + 16 + lo] = f2bf(acc11[r]);
    }
    // wave-private LDS is in-order: no barrier. Coalesced u32 stores.
    const u32* S32 = (const u32*)S;
    u32* Y32 = (u32*)Yv;            // bf16 Y, row stride 2048 u32
    #pragma unroll
    for (int i = lane; i < 512; i += 64) {
      int row = i >> 4, j = i & 15;
      Y32[(size_t)(m0 + row) * 2048 + (n0 >> 1) + j] = S32[row * 16 + j];
    }
  } else {
    float* Y = (float*)Yv;
    #pragma unroll
    for (int r = 0; r < 4; ++r) {
      Y[(size_t)(m0 + hi * 4 + r) * 4096 + n0 + lo] = acc00[r];
      Y[(size_t)(m0 + hi * 4 + r) * 4096 + n0 + 16 + lo] = acc01[r];
      Y[(size_t)(m0 + 16 + hi * 4 + r) * 4096 + n0 + lo] = acc10[r];
      Y[(size_t)(m0 + 16 + hi * 4 + r) * 4096 + n0 + 16 + lo] = acc11[r];
    }
  }
}

// ---- K2: depthwise 3x3, pad=1, on [576][64][64], bf16 in/out (fp32 math,
// identical fmaf order; one rounding on store). 1 ch/thread, 9216 blocks. ----
__global__ __launch_bounds__(256) void dwconv3(const u16* __restrict__ in,
                                               const float* __restrict__ w,
                                               u16* __restrict__ out) {
  int idx = blockIdx.x * 256 + threadIdx.x;  // c*4096 + p
  int c = idx >> 12;
  int p = idx & 4095;
  int y = p >> 6, x = p & 63;
  const float* wc = w + c * 9;
  const u16* ic = in + (size_t)c * 4096;
  float s = 0.f;
  #pragma unroll
  for (int i = 0; i < 3; ++i) {
    int yy = y + i - 1;
    if ((unsigned)yy >= 64u) continue;
    #pragma unroll
    for (int j = 0; j < 3; ++j) {
      int xx = x + j - 1;
      if ((unsigned)xx >= 64u) continue;
      s = fmaf(wc[i * 3 + j], bf2f(ic[yy * 64 + xx]), s);
    }
  }
  out[idx] = f2bf(s);
}

// ---- K3: fused normalize+pack (bf16 input). 256 blocks; per block: 128 px of
// one head. Threads 0..127: Q+K norm+pack ([h][p][32] bf16). 128..255: V pack
// with the A-frag key permutation. Row d==24 = ones -> denominator. ----
__global__ __launch_bounds__(256) void nvpack(const u16* __restrict__ qkv,
                                              u32* __restrict__ Qh32,
                                              u32* __restrict__ Kh32,
                                              u32* __restrict__ Vt32) {
  __shared__ u32 Ql[128 * 17];
  __shared__ u32 Kl[128 * 17];
  __shared__ u16 Vl[32 * 128];
  int t = threadIdx.x;
  int bid = blockIdx.x;          // 256 blocks
  int h = bid >> 5;
  int p0 = (bid & 31) << 7;      // 128-pixel tile
  u32* Vl32 = (u32*)Vl;
  const float QSC = 0.20412414523193154f * 1.4426950408889634f;  // 24^-0.5 * log2(e)
  if (t < 128) {
    int p = p0 + t;
    float qv[24], kv[24];
    float sq = 0.f, sk = 0.f;
    #pragma unroll
    for (int d = 0; d < 24; ++d) {
      qv[d] = bf2f(qkv[(size_t)(h * 24 + d) * 4096 + p]);
      sq = fmaf(qv[d], qv[d], sq);
    }
    #pragma unroll
    for (int d = 0; d < 24; ++d) {
      kv[d] = bf2f(qkv[(size_t)(192 + h * 24 + d) * 4096 + p]);
      sk = fmaf(kv[d], kv[d], sk);
    }
    float iq = QSC / fmaxf(sqrtf(sq), 1e-12f);  // F.normalize semantics
    float ik = 1.0f / fmaxf(sqrtf(sk), 1e-12f);
    u32* qrow = Ql + t * 17;
    u32* krow = Kl + t * 17;
    #pragma unroll
    for (int j = 0; j < 12; ++j) {
      qrow[j] = ((u32)f2bf(qv[2 * j + 1] * iq) << 16) | f2bf(qv[2 * j] * iq);
      krow[j] = ((u32)f2bf(kv[2 * j + 1] * ik) << 16) | f2bf(kv[2 * j] * ik);
    }
    #pragma unroll
    for (int j = 12; j < 16; ++j) { qrow[j] = 0; krow[j] = 0; }
  } else {
    int tl = t - 128;
    int p = p0 + tl;
    // A-frag key permutation
    int kp = (tl & ~63) | (tl & 32) | (((tl >> 2) & 3) << 3) |
             (((tl >> 4) & 1) << 2) | (tl & 3);
    #pragma unroll
    for (int d = 0; d < 24; ++d)
      Vl[d * 128 + kp] = qkv[(size_t)(384 + h * 24 + d) * 4096 + p];  // bf16 passthrough
    Vl[24 * 128 + kp] = 0x3F80;  // bf16 1.0
  }
  for (int i = t; i < 7 * 64; i += 256) Vl32[25 * 64 + i] = 0;  // zero d=25..31
  __syncthreads();
  size_t base = ((size_t)(h << 12) + p0) * 16;
  for (int i = t; i < 2048; i += 256) {
    u32 li = (i >> 4) * 17 + (i & 15);
    Qh32[base + i] = Ql[li];
    Kh32[base + i] = Kl[li];
  }
  for (int i = t; i < 2048; i += 256) {
    int d = i >> 6, c = i & 63;
    Vt32[(((size_t)(h * 32 + d)) << 11) + (p0 >> 1) + c] = Vl32[d * 64 + c];
  }
}

// exp2 each element of two f32x4 (S^T regs r=0..3 = keys quad*4+r), truncate to
// bf16, pack into a PV A-fragment (slots j=0..3 from a, j=4..7 from b).
__device__ __forceinline__ bf16x8 pexp(f32x4 a, f32x4 b) {
  union { u32 u[4]; bf16x8 v; } x;
  u32 a0 = __float_as_uint(__builtin_amdgcn_exp2f(a[0]));
  u32 a1 = __float_as_uint(__builtin_amdgcn_exp2f(a[1]));
  u32 a2 = __float_as_uint(__builtin_amdgcn_exp2f(a[2]));
  u32 a3 = __float_as_uint(__builtin_amdgcn_exp2f(a[3]));
  u32 b0 = __float_as_uint(__builtin_amdgcn_exp2f(b[0]));
  u32 b1 = __float_as_uint(__builtin_amdgcn_exp2f(b[1]));
  u32 b2 = __float_as_uint(__builtin_amdgcn_exp2f(b[2]));
  u32 b3 = __float_as_uint(__builtin_amdgcn_exp2f(b[3]));
  x.u[0] = __builtin_amdgcn_perm(a1, a0, 0x07060302u);
  x.u[1] = __builtin_amdgcn_perm(a3, a2, 0x07060302u);
  x.u[2] = __builtin_amdgcn_perm(b1, b0, 0x07060302u);
  x.u[3] = __builtin_amdgcn_perm(b3, b2, 0x07060302u);
  return x.v;
}

// ---- K4: flash attention, register-resident P, 8 Q-frags/wave (128 q), zero
// global intermediates. 512-thread blocks (8 waves = 8 K-eighths of 512 keys).
// Grid = 8 heads x 32 q-groups = 256 blocks (1/CU). R14 lesson: per-wave ILP
// beats occupancy (4-frag@16w/CU >> 2-frag@32w/CU); 8 frags doubles the
// independent S->exp->PV chains per wave AND halves K/V L2 traffic (268->134
// MB). VGPR ~150 < 170 cap of (512,3) — K single-buffered (R16: dbuf neutral).
// Epilogue: two 64-row passes through the 57 KB staging buffer.
__global__ __launch_bounds__(512, 3) void attn(const u16* __restrict__ Qh,
                                               const u16* __restrict__ Kh,
                                               const u16* __restrict__ Vt,
                                               u16* __restrict__ Pt) {
  __shared__ float Sf[8 * 64 * 28];  // 57344 B epilogue staging (per pass)
  __shared__ u16 Pb[64 * 24];        // 3072 B bf16 out staging
  int tid = threadIdx.x;
  int wave = tid >> 6, lane = tid & 63;
  int lo = lane & 15, hi = lane >> 4;
  int b = blockIdx.x;
  int head = b & 7;              // head == XCD (round-robin) -> K/V L2-resident
  int q0 = (b >> 3) << 7;        // 128 queries per block

  const u16* Kb = Kh + ((size_t)head << 17);
  const u16* Vb = Vt + ((size_t)head << 17);

  size_t qrow = (size_t)(head << 12) + q0 + lo;
  bf16x8 qf[8];
  #pragma unroll
  for (int f = 0; f < 8; ++f)
    qf[f] = *(const bf16x8*)(Qh + ((qrow + f * 16) << 5) + hi * 8);

  f32x4 zz = {0.f, 0.f, 0.f, 0.f};
  f32x4 oA[8], oB[8];
  #pragma unroll
  for (int f = 0; f < 8; ++f) { oA[f] = zz; oB[f] = zz; }

  int kbase = wave << 9;                        // 512 keys per wave

  for (int it = 0; it < 8; ++it) {              // 8 tiles of 64 keys
    int k0 = kbase + it * 64;
    bf16x8 kf[4], vf[4];
    #pragma unroll
    for (int j = 0; j < 4; ++j)
      kf[j] = *(const bf16x8*)(Kb + (((size_t)(k0 + j * 16 + lo)) << 5) + hi * 8);
    vf[0] = *(const bf16x8*)(Vb + (((size_t)(lo)) << 12) + k0 + hi * 8);
    vf[1] = *(const bf16x8*)(Vb + (((size_t)(16 + lo)) << 12) + k0 + hi * 8);
    vf[2] = *(const bf16x8*)(Vb + (((size_t)(lo)) << 12) + k0 + 32 + hi * 8);
    vf[3] = *(const bf16x8*)(Vb + (((size_t)(16 + lo)) << 12) + k0 + 32 + hi * 8);
    #pragma unroll
    for (int f = 0; f < 8; ++f) {
      f32x4 t0 = __builtin_amdgcn_mfma_f32_16x16x32_bf16(kf[0], qf[f], zz, 0, 0, 0);
      f32x4 t1 = __builtin_amdgcn_mfma_f32_16x16x32_bf16(kf[1], qf[f], zz, 0, 0, 0);
      f32x4 t2 = __builtin_amdgcn_mfma_f32_16x16x32_bf16(kf[2], qf[f], zz, 0, 0, 0);
      f32x4 t3 = __builtin_amdgcn_mfma_f32_16x16x32_bf16(kf[3], qf[f], zz, 0, 0, 0);
      bf16x8 a0 = pexp(t0, t1);
      bf16x8 a1 = pexp(t2, t3);
      oA[f] = __builtin_amdgcn_mfma_f32_16x16x32_bf16(a0, vf[0], oA[f], 0, 0, 0);
      oB[f] = __builtin_amdgcn_mfma_f32_16x16x32_bf16(a0, vf[1], oB[f], 0, 0, 0);
      oA[f] = __builtin_amdgcn_mfma_f32_16x16x32_bf16(a1, vf[2], oA[f], 0, 0, 0);
      oB[f] = __builtin_amdgcn_mfma_f32_16x16x32_bf16(a1, vf[3], oB[f], 0, 0, 0);
    }
  }

  // epilogue: two 64-row passes (frags 0..3, then 4..7).
  const u32* Pb32 = (const u32*)Pb;
  u32* Pt32 = (u32*)Pt;
  #pragma unroll
  for (int pass = 0; pass < 2; ++pass) {
    // stage fp32 C-layout (num cols 0..23, den col 24) into OWN strip
    int sb = wave * (64 * 28);
    #pragma unroll
    for (int fl = 0; fl < 4; ++fl) {
      int f = pass * 4 + fl;
      #pragma unroll
      for (int r = 0; r < 4; ++r) {
        int row = fl * 16 + hi * 4 + r;
        Sf[sb + row * 28 + lo] = oA[f][r];
        if (lo < 8) Sf[sb + row * 28 + 16 + lo] = oB[f][r];
        if (lo == 8) Sf[sb + row * 28 + 24] = oB[f][r];   // ones-row = denominator
      }
    }
    __syncthreads();   // staging complete (and, pass 1: prior Pb reads complete)
    // reduce the 8 K-eighths, normalize, stage bf16 per-pixel rows
    int q = tid & 63;
    int d0 = tid >> 6;             // 0..7
    int base0 = q * 28;
    const int SS = 64 * 28;
    float den = 0.f;
    #pragma unroll
    for (int s = 0; s < 8; ++s) den += Sf[base0 + s * SS + 24];
    float inv = 1.0f / den;
    #pragma unroll
    for (int dp = 0; dp < 3; ++dp) {
      int dd = dp * 8 + d0;
      float v = 0.f;
      #pragma unroll
      for (int s = 0; s < 8; ++s) v += Sf[base0 + s * SS + dd];
      Pb[q * 24 + dd] = f2bf(v * inv);
    }
    __syncthreads();   // Pb complete; Sf reads complete (safe to restage)
    // coalesced u32 stores of this pass's [64 px][12 u32] strip
    for (int i = tid; i < 768; i += 512) {
      int qq = i / 12, j = i - qq * 12;
      Pt32[(size_t)(q0 + pass * 64 + qq) * 96 + head * 12 + j] = Pb32[qq * 12 + j];
    }
  }
}

extern "C" void kernel_launch(void* const* d_in, const int* in_sizes, int n_in,
                              void* d_out, int out_size, void* d_ws, size_t ws_size,
                              hipStream_t stream) {
  const float* x      = (const float*)d_in[0];  // [192][4096]
  const float* w_qkv  = (const float*)d_in[1];  // [576][192]
  const float* w_dw   = (const float*)d_in[2];  // [576][9]
  const float* w_proj = (const float*)d_in[3];  // [192][192]
  float* out = (float*)d_out;                   // [192][4096] fp32

  char* ws = (char*)d_ws;
  u16*   qkv    = (u16*)  (ws);                 // 4718592 bf16 (dead after dwconv3)
  u16*   qkvd   = (u16*)  (ws + 4718592);       // 4718592 bf16 (dead after nvpack)
  u16*   Qh     = (u16*)  (ws + 18874368);      // 2097152
  u16*   Kh     = (u16*)  (ws + 20971520);      // 2097152
  u16*   Vt     = (u16*)  (ws + 23068672);      // 2097152  (end 25165824)
  u16*   Xt     = (u16*)  (ws + 25165824);      // 1572864  (bf16 X^T)
  u16*   Wb     = (u16*)  (ws + 26738688);      // 221184
  u16*   Wpb    = (u16*)  (ws + 26959872);      // 73728    (end 27033600)
  u16*   Pt     = (u16*)  (ws + 13107200);      // 1572864  (bf16 attn-out^T)

  // prep: X transpose->bf16 (128) + w_qkv->bf16 (54) + w_proj->bf16 (18)
  prep<<<dim3(200), 256, 0, stream>>>(x, w_qkv, w_proj, Xt, Wb, Wpb);
  // qkv GEMM on MFMA, bf16 out: grid (32 n-tiles, 18 m-tiles)
  mqkv<true><<<dim3(32, 18), 256, 0, stream>>>(Wb, Xt, qkv);
  dwconv3<<<dim3(9216), 256, 0, stream>>>(qkv, w_dw, qkvd);
  nvpack<<<dim3(256), 256, 0, stream>>>(qkvd, (u32*)Qh, (u32*)Kh, (u32*)Vt);
  // 256 blocks x 512 threads; 8 q-frags/wave, register-resident P
  attn<<<dim3(256), 512, 0, stream>>>(Qh, Kh, Vt, Pt);
  // proj GEMM on MFMA, fp32 out: grid (32 n-tiles, 6 m-tiles)
  mqkv<false><<<dim3(32, 6), 256, 0, stream>>>(Wpb, Pt, out);
}